// Round 1
// baseline (713.255 us; speedup 1.0000x reference)
//
#include <hip/hip_runtime.h>
#include <hip/hip_bf16.h>
#include <stdint.h>

typedef _Float16 f16;
typedef __attribute__((ext_vector_type(8))) _Float16 f16x8;
typedef __attribute__((ext_vector_type(4))) _Float16 f16x4;
typedef __attribute__((ext_vector_type(4))) float f32x4;

#define GLOBAL_AS __attribute__((address_space(1)))
#define LDS_AS __attribute__((address_space(3)))

#define D_DIM 768
#define NTOK 1024
#define NSLOT 16
#define NB 32
#define NTOT (NB*NTOK)   // 32768
#define HDIM 512
#define INNER 3072
#define SCALE_D 0.03608439182435161f   // 768^-0.5
#define SCALE_H 0.125f                 // 64^-0.5

// ---------- MFMA GEMM 64x64, BK=128 (4 panels), split-K ----------
// OUT: 1 = f16 store, 2 = f32 atomicAdd.
template<int OUT>
__global__ __launch_bounds__(256) void mgemm64_k(
    const f16* __restrict__ A, const f16* __restrict__ Bt,
    void* __restrict__ Cout, int M, int N, int K, int Kc)
{
  __shared__ __align__(16) f16 As[64*128];
  __shared__ __align__(16) f16 Bs[64*128];
  const int tid = threadIdx.x;
  const int lane = tid & 63;
  const int wave = tid >> 6;
  const int m0 = blockIdx.x*64, n0 = blockIdx.y*64;
  const int kbeg = blockIdx.z * Kc;
  const int wm = (wave>>1)*32, wn = (wave&1)*32;
  const int quad = lane>>4, l16 = lane&15;

  const int sr = tid>>2;
  const int sc = (tid&3)*8;
  const f16* gA = A  + (size_t)(m0+sr)*K + kbeg + sc;
  const f16* gB = Bt + (size_t)(n0+sr)*K + kbeg + sc;
  LDS_AS f16* lA = (LDS_AS f16*)&As[(size_t)tid*8];
  LDS_AS f16* lB = (LDS_AS f16*)&Bs[(size_t)tid*8];

  const f16* fA0 = &As[(wm + l16)*32 + quad*8];
  const f16* fB0 = &Bs[(wn + l16)*32 + quad*8];

  f32x4 acc[2][2] = {};

  for (int k0 = 0; k0 < Kc; k0 += 128){
    #pragma unroll
    for (int p=0;p<4;++p){
      __builtin_amdgcn_global_load_lds((const GLOBAL_AS void*)(gA + k0 + p*32),
                                       (LDS_AS void*)(lA + (size_t)p*2048), 16, 0, 0);
      __builtin_amdgcn_global_load_lds((const GLOBAL_AS void*)(gB + k0 + p*32),
                                       (LDS_AS void*)(lB + (size_t)p*2048), 16, 0, 0);
    }
    __syncthreads();
    #pragma unroll
    for (int p=0;p<4;++p){
      f16x8 a0 = *(const f16x8*)(fA0 + p*2048);
      f16x8 a1 = *(const f16x8*)(fA0 + p*2048 + 16*32);
      f16x8 b0 = *(const f16x8*)(fB0 + p*2048);
      f16x8 b1 = *(const f16x8*)(fB0 + p*2048 + 16*32);
      acc[0][0] = __builtin_amdgcn_mfma_f32_16x16x32_f16(a0,b0,acc[0][0],0,0,0);
      acc[0][1] = __builtin_amdgcn_mfma_f32_16x16x32_f16(a0,b1,acc[0][1],0,0,0);
      acc[1][0] = __builtin_amdgcn_mfma_f32_16x16x32_f16(a1,b0,acc[1][0],0,0,0);
      acc[1][1] = __builtin_amdgcn_mfma_f32_16x16x32_f16(a1,b1,acc[1][1],0,0,0);
    }
    __syncthreads();
  }
  #pragma unroll
  for (int mt=0;mt<2;++mt){
    #pragma unroll
    for (int nt=0;nt<2;++nt){
      int gm = m0 + wm + mt*16 + quad*4;
      int gn = n0 + wn + nt*16 + l16;
      #pragma unroll
      for (int r=0;r<4;++r){
        float c = acc[mt][nt][r];
        size_t idx = (size_t)(gm+r)*N + gn;
        if (OUT==1) ((f16*)Cout)[idx] = (f16)c;
        else        atomicAdd(&((float*)Cout)[idx], c);
      }
    }
  }
}

// ---------- W1 + GLU fused ----------
__global__ __launch_bounds__(256) void w1glu_k(
    const f16* __restrict__ A, const f16* __restrict__ W1T,
    f16* __restrict__ act, int M)
{
  __shared__ __align__(16) f16 As[64*128];
  __shared__ __align__(16) f16 Bu[64*128];
  __shared__ __align__(16) f16 Bg[64*128];
  const int K = 768;
  const int tid = threadIdx.x;
  const int lane = tid & 63;
  const int wave = tid >> 6;
  const int m0 = blockIdx.x*64, n0 = blockIdx.y*64;
  const int wm = (wave>>1)*32, wn = (wave&1)*32;
  const int quad = lane>>4, l16 = lane&15;

  const int sr = tid>>2;
  const int sc = (tid&3)*8;
  const f16* gA  = A   + (size_t)(m0+sr)*K + sc;
  const f16* gBu = W1T + (size_t)(n0+sr)*K + sc;
  const f16* gBg = W1T + (size_t)(3072+n0+sr)*K + sc;
  LDS_AS f16* lA  = (LDS_AS f16*)&As[(size_t)tid*8];
  LDS_AS f16* lBu = (LDS_AS f16*)&Bu[(size_t)tid*8];
  LDS_AS f16* lBg = (LDS_AS f16*)&Bg[(size_t)tid*8];

  const f16* fA0 = &As[(wm + l16)*32 + quad*8];
  const f16* fU0 = &Bu[(wn + l16)*32 + quad*8];
  const f16* fG0 = &Bg[(wn + l16)*32 + quad*8];

  f32x4 accU[2][2] = {};
  f32x4 accG[2][2] = {};

  for (int k0 = 0; k0 < K; k0 += 128){
    #pragma unroll
    for (int p=0;p<4;++p){
      __builtin_amdgcn_global_load_lds((const GLOBAL_AS void*)(gA  + k0 + p*32),
                                       (LDS_AS void*)(lA  + (size_t)p*2048), 16, 0, 0);
      __builtin_amdgcn_global_load_lds((const GLOBAL_AS void*)(gBu + k0 + p*32),
                                       (LDS_AS void*)(lBu + (size_t)p*2048), 16, 0, 0);
      __builtin_amdgcn_global_load_lds((const GLOBAL_AS void*)(gBg + k0 + p*32),
                                       (LDS_AS void*)(lBg + (size_t)p*2048), 16, 0, 0);
    }
    __syncthreads();
    #pragma unroll
    for (int p=0;p<4;++p){
      f16x8 a0 = *(const f16x8*)(fA0 + p*2048);
      f16x8 a1 = *(const f16x8*)(fA0 + p*2048 + 16*32);
      f16x8 u0 = *(const f16x8*)(fU0 + p*2048);
      f16x8 u1 = *(const f16x8*)(fU0 + p*2048 + 16*32);
      f16x8 g0 = *(const f16x8*)(fG0 + p*2048);
      f16x8 g1 = *(const f16x8*)(fG0 + p*2048 + 16*32);
      accU[0][0] = __builtin_amdgcn_mfma_f32_16x16x32_f16(a0,u0,accU[0][0],0,0,0);
      accU[0][1] = __builtin_amdgcn_mfma_f32_16x16x32_f16(a0,u1,accU[0][1],0,0,0);
      accU[1][0] = __builtin_amdgcn_mfma_f32_16x16x32_f16(a1,u0,accU[1][0],0,0,0);
      accU[1][1] = __builtin_amdgcn_mfma_f32_16x16x32_f16(a1,u1,accU[1][1],0,0,0);
      accG[0][0] = __builtin_amdgcn_mfma_f32_16x16x32_f16(a0,g0,accG[0][0],0,0,0);
      accG[0][1] = __builtin_amdgcn_mfma_f32_16x16x32_f16(a0,g1,accG[0][1],0,0,0);
      accG[1][0] = __builtin_amdgcn_mfma_f32_16x16x32_f16(a1,g0,accG[1][0],0,0,0);
      accG[1][1] = __builtin_amdgcn_mfma_f32_16x16x32_f16(a1,g1,accG[1][1],0,0,0);
    }
    __syncthreads();
  }
  #pragma unroll
  for (int mt=0;mt<2;++mt){
    #pragma unroll
    for (int nt=0;nt<2;++nt){
      int gm = m0 + wm + mt*16 + quad*4;
      int gn = n0 + wn + nt*16 + l16;
      #pragma unroll
      for (int r=0;r<4;++r){
        float u = accU[mt][nt][r];
        float g = accG[mt][nt][r];
        float sg = g / (1.0f + __expf(-g));
        act[(size_t)(gm+r)*INNER + gn] = (f16)(u*sg);
      }
    }
  }
}

// ---------- MFMA dots (q_eff @ xn^T) + inverted softmax + EPS + partial rowsum ----------
__global__ __launch_bounds__(256) void dots_k(
    const f16* __restrict__ Q,    // [32,16,768] q_eff
    const f16* __restrict__ Xn,   // [32768,768]
    f16* __restrict__ attn,       // [32,16,1024] f16
    float* __restrict__ rsPart)   // [32][16 jt][16 i]
{
  __shared__ __align__(16) f16 qf[16*768];
  __shared__ __align__(16) f16 ks[64*128];
  __shared__ float rpart[4][16];
  const int b = blockIdx.x, jt = blockIdx.y;
  const int tid = threadIdx.x;
  const int lane = tid & 63;
  const int w = tid >> 6;
  const int quad = lane>>4, l16 = lane&15;

  #pragma unroll
  for (int c=0;c<6;++c){
    int p = c*256 + tid;
    int ki = p >> 6, qd = (p >> 4) & 3, rw = p & 15;
    f16x8 v = *(const f16x8*)(Q + ((size_t)(b*NSLOT+rw))*D_DIM + ki*32 + qd*8);
    *(f16x8*)&qf[(size_t)p*8] = v;
  }

  const f16* gK = Xn + ((size_t)(b*NTOK + jt*64 + (tid>>2)))*D_DIM + (tid&3)*8;
  LDS_AS f16* lK = (LDS_AS f16*)&ks[(size_t)tid*8];

  f32x4 acc = {};
  for (int it=0; it<6; ++it){
    #pragma unroll
    for (int p=0;p<4;++p)
      __builtin_amdgcn_global_load_lds((const GLOBAL_AS void*)(gK + it*128 + p*32),
                                       (LDS_AS void*)(lK + (size_t)p*2048), 16, 0, 0);
    __syncthreads();
    #pragma unroll
    for (int p=0;p<4;++p){
      f16x8 a  = *(const f16x8*)&qf[(((size_t)(it*4+p)*4 + quad)*16 + l16)*8];
      f16x8 bf = *(const f16x8*)&ks[(size_t)p*2048 + (w*16+l16)*32 + quad*8];
      acc = __builtin_amdgcn_mfma_f32_16x16x32_f16(a, bf, acc, 0, 0, 0);
    }
    __syncthreads();
  }

  float v0 = acc[0]*SCALE_D, v1 = acc[1]*SCALE_D, v2 = acc[2]*SCALE_D, v3 = acc[3]*SCALE_D;
  float mx = fmaxf(fmaxf(v0,v1), fmaxf(v2,v3));
  mx = fmaxf(mx, __shfl_xor(mx, 16));
  mx = fmaxf(mx, __shfl_xor(mx, 32));
  float e0 = __expf(v0-mx), e1 = __expf(v1-mx), e2 = __expf(v2-mx), e3 = __expf(v3-mx);
  float s = e0+e1+e2+e3;
  s += __shfl_xor(s, 16);
  s += __shfl_xor(s, 32);
  float inv = 1.0f/s;
  float a0 = e0*inv + 1e-8f, a1 = e1*inv + 1e-8f, a2 = e2*inv + 1e-8f, a3 = e3*inv + 1e-8f;

  int jcol = jt*64 + w*16 + l16;
  int ibase = b*NSLOT + quad*4;
  attn[(size_t)(ibase+0)*NTOK + jcol] = (f16)a0;
  attn[(size_t)(ibase+1)*NTOK + jcol] = (f16)a1;
  attn[(size_t)(ibase+2)*NTOK + jcol] = (f16)a2;
  attn[(size_t)(ibase+3)*NTOK + jcol] = (f16)a3;

  float t0=a0, t1=a1, t2=a2, t3=a3;
  #pragma unroll
  for (int m=1;m<16;m<<=1){
    t0 += __shfl_xor(t0, m);
    t1 += __shfl_xor(t1, m);
    t2 += __shfl_xor(t2, m);
    t3 += __shfl_xor(t3, m);
  }
  if (l16 == 0){
    rpart[w][quad*4+0] = t0;
    rpart[w][quad*4+1] = t1;
    rpart[w][quad*4+2] = t2;
    rpart[w][quad*4+3] = t3;
  }
  __syncthreads();
  if (tid < 16){
    float ss = rpart[0][tid] + rpart[1][tid] + rpart[2][tid] + rpart[3][tid];
    rsPart[(size_t)((b*16 + jt)<<4) + tid] = ss;
  }
}

// ---------- t = (attn @ xn)/rowsum, FUSED with upd-partial: acc += t_slice @ Wv ----------
// grid (32 b, 12 d-tiles of 64). accb must be pre-loaded with slots.
__global__ __launch_bounds__(256) void attnv_k(
    const f16* __restrict__ attn,   // [32,16,1024]
    const float* __restrict__ rsPart,
    const f16* __restrict__ XnT,    // [768, 32768]
    const f16* __restrict__ WvT,    // [768 n][768 k]
    float* __restrict__ accb)       // [512,768] f32, slots pre-loaded, atomic +=
{
  __shared__ __align__(16) f16 Asl[16*128];
  __shared__ __align__(16) f16 Bsl[64*128];
  __shared__ float rsum[16];
  __shared__ __align__(16) f16 tl[16][80];
  const int b = blockIdx.x, d0 = blockIdx.y*64;
  const int tid = threadIdx.x;
  const int lane = tid & 63;
  const int w = tid >> 6;
  const int quad = lane>>4, l16 = lane&15;

  if (tid < 16){
    float s = 0.f;
    #pragma unroll
    for (int jt=0;jt<16;++jt) s += rsPart[(size_t)((b*16 + jt)<<4) + tid];
    rsum[tid] = s;
  }

  const int pa = tid>>6, ta = tid&63;
  const f16* gA = attn + ((size_t)(b*NSLOT + (ta>>2)))*NTOK + pa*32 + (ta&3)*8;
  LDS_AS f16* lA = (LDS_AS f16*)&Asl[(size_t)pa*512 + ta*8];
  const f16* gB = XnT + ((size_t)(d0 + (tid>>2)))*NTOT + b*NTOK + (tid&3)*8;
  LDS_AS f16* lB = (LDS_AS f16*)&Bsl[(size_t)tid*8];

  f32x4 acc = {};
  for (int it=0; it<8; ++it){
    __builtin_amdgcn_global_load_lds((const GLOBAL_AS void*)(gA + it*128),
                                     (LDS_AS void*)lA, 16, 0, 0);
    #pragma unroll
    for (int p=0;p<4;++p)
      __builtin_amdgcn_global_load_lds((const GLOBAL_AS void*)(gB + it*128 + p*32),
                                       (LDS_AS void*)(lB + (size_t)p*2048), 16, 0, 0);
    __syncthreads();
    #pragma unroll
    for (int p=0;p<4;++p){
      f16x8 a  = *(const f16x8*)&Asl[(size_t)p*512 + l16*32 + quad*8];
      f16x8 bf = *(const f16x8*)&Bsl[(size_t)p*2048 + (w*16+l16)*32 + quad*8];
      acc = __builtin_amdgcn_mfma_f32_16x16x32_f16(a, bf, acc, 0, 0, 0);
    }
    __syncthreads();
  }
  // t slice [16 i][64 d-local] -> LDS (f16)
  const int dloc = w*16 + l16;
  #pragma unroll
  for (int r=0;r<4;++r)
    tl[quad*4+r][dloc] = (f16)(acc[r] / rsum[quad*4+r]);
  __syncthreads();
  // partial upd: acc[b] += t_slice @ Wv[d0:d0+64, :]
  f16x8 af0 = *(const f16x8*)&tl[l16][quad*8];
  f16x8 af1 = *(const f16x8*)&tl[l16][32 + quad*8];
  const f16* bp = WvT + (size_t)l16*D_DIM + d0 + quad*8;
  float* up = accb + (size_t)(b*NSLOT + quad*4)*D_DIM + l16;
  #pragma unroll
  for (int j=0;j<12;++j){
    int n0 = (w*12 + j)*16;
    f16x8 b0 = *(const f16x8*)(bp + (size_t)n0*D_DIM);
    f16x8 b1 = *(const f16x8*)(bp + (size_t)n0*D_DIM + 32);
    f32x4 c = {};
    c = __builtin_amdgcn_mfma_f32_16x16x32_f16(af0, b0, c, 0,0,0);
    c = __builtin_amdgcn_mfma_f32_16x16x32_f16(af1, b1, c, 0,0,0);
    #pragma unroll
    for (int r=0;r<4;++r) atomicAdd(up + (size_t)r*D_DIM + n0, c[r]);
  }
}

// ---------- wave-per-row LN (4 rows/block), f16 out ----------
__global__ __launch_bounds__(256) void lnw_k(
    const float* __restrict__ X,
    const float* __restrict__ g, const float* __restrict__ bb,
    f16* __restrict__ out)
{
  const int lane = threadIdx.x & 63;
  const size_t row = (size_t)blockIdx.x*4 + (threadIdx.x>>6);
  const float* x = X + row*D_DIM;
  float4 v[3]; float s=0.f, ss=0.f;
  #pragma unroll
  for (int t=0;t<3;++t){
    v[t] = *(const float4*)(x + lane*4 + t*256);
    s  += v[t].x+v[t].y+v[t].z+v[t].w;
    ss += v[t].x*v[t].x+v[t].y*v[t].y+v[t].z*v[t].z+v[t].w*v[t].w;
  }
  #pragma unroll
  for (int m=1;m<64;m<<=1){ s += __shfl_xor(s,m); ss += __shfl_xor(ss,m); }
  float mean = s*(1.0f/768.0f);
  float inv  = rsqrtf(ss*(1.0f/768.0f) - mean*mean + 1e-5f);
  #pragma unroll
  for (int t=0;t<3;++t){
    int c0 = lane*4 + t*256;
    float4 gg = *(const float4*)(g + c0);
    float4 bv = *(const float4*)(bb + c0);
    f16x4 h4;
    h4.x = (f16)((v[t].x-mean)*inv*gg.x + bv.x);
    h4.y = (f16)((v[t].y-mean)*inv*gg.y + bv.y);
    h4.z = (f16)((v[t].z-mean)*inv*gg.z + bv.z);
    h4.w = (f16)((v[t].w-mean)*inv*gg.w + bv.w);
    *(f16x4*)(out + row*D_DIM + c0) = h4;
  }
}

// ---------- wave-per-row double LN: out1=LN(X,g1,b1) f32 (+acc copy), out2=LN(out1,g2,b2) f16 ----------
template<bool WACC>
__global__ __launch_bounds__(256) void lnlnw_k(
    const float* __restrict__ X,
    const float* __restrict__ g1, const float* __restrict__ b1,
    const float* __restrict__ g2, const float* __restrict__ b2,
    float* __restrict__ out1, f16* __restrict__ out2, float* __restrict__ acc)
{
  const int lane = threadIdx.x & 63;
  const size_t row = (size_t)blockIdx.x*4 + (threadIdx.x>>6);
  const float* x = X + row*D_DIM;
  float4 v[3]; float s=0.f, ss=0.f;
  #pragma unroll
  for (int t=0;t<3;++t){
    v[t] = *(const float4*)(x + lane*4 + t*256);
    s  += v[t].x+v[t].y+v[t].z+v[t].w;
    ss += v[t].x*v[t].x+v[t].y*v[t].y+v[t].z*v[t].z+v[t].w*v[t].w;
  }
  #pragma unroll
  for (int m=1;m<64;m<<=1){ s += __shfl_xor(s,m); ss += __shfl_xor(ss,m); }
  float mean = s*(1.0f/768.0f);
  float inv  = rsqrtf(ss*(1.0f/768.0f) - mean*mean + 1e-5f);
  float y[3][4]; float s2=0.f, ss2=0.f;
  #pragma unroll
  for (int t=0;t<3;++t){
    int c0 = lane*4 + t*256;
    float4 gg = *(const float4*)(g1 + c0);
    float4 bv = *(const float4*)(b1 + c0);
    y[t][0] = (v[t].x-mean)*inv*gg.x + bv.x;
    y[t][1] = (v[t].y-mean)*inv*gg.y + bv.y;
    y[t][2] = (v[t].z-mean)*inv*gg.z + bv.z;
    y[t][3] = (v[t].w-mean)*inv*gg.w + bv.w;
    float4 o = { y[t][0], y[t][1], y[t][2], y[t][3] };
    *(float4*)(out1 + row*D_DIM + c0) = o;
    if (WACC) *(float4*)(acc + row*D_DIM + c0) = o;
    s2  += y[t][0]+y[t][1]+y[t][2]+y[t][3];
    ss2 += y[t][0]*y[t][0]+y[t][1]*y[t][1]+y[t][2]*y[t][2]+y[t][3]*y[t][3];
  }
  #pragma unroll
  for (int m=1;m<64;m<<=1){ s2 += __shfl_xor(s2,m); ss2 += __shfl_xor(ss2,m); }
  float mean2 = s2*(1.0f/768.0f);
  float inv2  = rsqrtf(ss2*(1.0f/768.0f) - mean2*mean2 + 1e-5f);
  #pragma unroll
  for (int t=0;t<3;++t){
    int c0 = lane*4 + t*256;
    float4 gg = *(const float4*)(g2 + c0);
    float4 bv = *(const float4*)(b2 + c0);
    f16x4 h4;
    h4.x = (f16)((y[t][0]-mean2)*inv2*gg.x + bv.x);
    h4.y = (f16)((y[t][1]-mean2)*inv2*gg.y + bv.y);
    h4.z = (f16)((y[t][2]-mean2)*inv2*gg.z + bv.z);
    h4.w = (f16)((y[t][3]-mean2)*inv2*gg.w + bv.w);
    *(f16x4*)(out2 + row*D_DIM + c0) = h4;
  }
}

// ---------- slots init + LN(ns) fused; also writes acc copy ----------
__global__ __launch_bounds__(256) void slotsinit_k(
    const float* __restrict__ noise, const float* __restrict__ mu,
    const float* __restrict__ ls,
    const float* __restrict__ nsg, const float* __restrict__ nsb,
    float* __restrict__ slots, float* __restrict__ accb, f16* __restrict__ tmp2)
{
  const int lane = threadIdx.x & 63;
  const size_t row = (size_t)blockIdx.x*4 + (threadIdx.x>>6);
  float4 v[3]; float s=0.f, ss=0.f;
  #pragma unroll
  for (int t=0;t<3;++t){
    int c0 = lane*4 + t*256;
    float4 nz = *(const float4*)(noise + row*D_DIM + c0);
    float4 m4 = *(const float4*)(mu + c0);
    float4 l4 = *(const float4*)(ls + c0);
    v[t].x = m4.x + __expf(l4.x)*nz.x;
    v[t].y = m4.y + __expf(l4.y)*nz.y;
    v[t].z = m4.z + __expf(l4.z)*nz.z;
    v[t].w = m4.w + __expf(l4.w)*nz.w;
    *(float4*)(slots + row*D_DIM + c0) = v[t];
    *(float4*)(accb  + row*D_DIM + c0) = v[t];
    s  += v[t].x+v[t].y+v[t].z+v[t].w;
    ss += v[t].x*v[t].x+v[t].y*v[t].y+v[t].z*v[t].z+v[t].w*v[t].w;
  }
  #pragma unroll
  for (int m=1;m<64;m<<=1){ s += __shfl_xor(s,m); ss += __shfl_xor(ss,m); }
  float mean = s*(1.0f/768.0f);
  float inv  = rsqrtf(ss*(1.0f/768.0f) - mean*mean + 1e-5f);
  #pragma unroll
  for (int t=0;t<3;++t){
    int c0 = lane*4 + t*256;
    float4 gg = *(const float4*)(nsg + c0);
    float4 bv = *(const float4*)(nsb + c0);
    f16x4 h4;
    h4.x = (f16)((v[t].x-mean)*inv*gg.x + bv.x);
    h4.y = (f16)((v[t].y-mean)*inv*gg.y + bv.y);
    h4.z = (f16)((v[t].z-mean)*inv*gg.z + bv.z);
    h4.w = (f16)((v[t].w-mean)*inv*gg.w + bv.w);
    *(f16x4*)(tmp2 + row*D_DIM + c0) = h4;
  }
}

// ---------- encoder self-attn FUSED with Wo partial: hbuf += o_slice @ Wo[h-slice] ----------
__global__ __launch_bounds__(256) void encwo_k(
    const f16* __restrict__ QA, const f16* __restrict__ KA,
    const f16* __restrict__ VA, int QSTR,
    const f16* __restrict__ WoT,   // [768 n][512 k]
    float* __restrict__ hb)        // [512,768] f32, atomic +=
{
  __shared__ float qs[16][68], ks[16][68], vs[16][68], ps[16][20];
  __shared__ __align__(16) f16 ol[16][80];
  const int b = blockIdx.x, h = blockIdx.y;
  const int tid = threadIdx.x;
  {
    int i = tid>>4, dd=(tid&15)*4;
    size_t base = ((size_t)(b*NSLOT+i))*QSTR + h*64 + dd;
    f16x4 uq = *(const f16x4*)(QA + base);
    f16x4 uk = *(const f16x4*)(KA + base);
    f16x4 uv = *(const f16x4*)(VA + base);
    float4 fq = { (float)uq.x, (float)uq.y, (float)uq.z, (float)uq.w };
    float4 fk = { (float)uk.x, (float)uk.y, (float)uk.z, (float)uk.w };
    float4 fv = { (float)uv.x, (float)uv.y, (float)uv.z, (float)uv.w };
    *(float4*)&qs[i][dd]=fq; *(float4*)&ks[i][dd]=fk; *(float4*)&vs[i][dd]=fv;
  }
  __syncthreads();
  {
    int i = tid>>4, j = tid&15;
    float s=0.f;
    #pragma unroll 8
    for (int d=0; d<64; ++d) s += qs[i][d]*ks[j][d];
    ps[i][j] = s*SCALE_H;
  }
  __syncthreads();
  if (tid < 16){
    int i = tid;
    float mx=-1e30f;
    #pragma unroll
    for (int j=0;j<16;++j) mx = fmaxf(mx, ps[i][j]);
    float sm=0.f;
    #pragma unroll
    for (int j=0;j<16;++j){ float e=__expf(ps[i][j]-mx); ps[i][j]=e; sm+=e; }
    float inv=1.0f/sm;
    #pragma unroll
    for (int j=0;j<16;++j) ps[i][j]*=inv;
  }
  __syncthreads();
  {
    int i = tid>>4, dq=(tid&15)*4;
    float a0=0,a1=0,a2=0,a3=0;
    #pragma unroll
    for (int j=0;j<16;++j){
      float p = ps[i][j];
      a0+=p*vs[j][dq+0]; a1+=p*vs[j][dq+1]; a2+=p*vs[j][dq+2]; a3+=p*vs[j][dq+3];
    }
    f16x4 o4 = { (f16)a0, (f16)a1, (f16)a2, (f16)a3 };
    *(f16x4*)&ol[i][dq] = o4;
  }
  __syncthreads();
  const int lane = tid & 63, w = tid>>6, quad = lane>>4, l16 = lane&15;
  f16x8 af0 = *(const f16x8*)&ol[l16][quad*8];
  f16x8 af1 = *(const f16x8*)&ol[l16][32 + quad*8];
  const f16* bp = WoT + (size_t)l16*HDIM + h*64 + quad*8;
  float* hp = hb + (size_t)(b*NSLOT + quad*4)*D_DIM + l16;
  #pragma unroll
  for (int j=0;j<12;++j){
    int n0 = (w*12 + j)*16;
    f16x8 b0 = *(const f16x8*)(bp + (size_t)n0*HDIM);
    f16x8 b1 = *(const f16x8*)(bp + (size_t)n0*HDIM + 32);
    f32x4 c = {};
    c = __builtin_amdgcn_mfma_f32_16x16x32_f16(af0, b0, c, 0,0,0);
    c = __builtin_amdgcn_mfma_f32_16x16x32_f16(af1, b1, c, 0,0,0);
    #pragma unroll
    for (int r=0;r<4;++r) atomicAdd(hp + (size_t)r*D_DIM + n0, c[r]);
  }
}

// ---------- f16 transpose: out[C][R] = in[R][C] ----------
__global__ __launch_bounds__(256) void transp_k(
    const f16* __restrict__ in, f16* __restrict__ out, int R, int C)
{
  __shared__ f16 T[64][72];
  const int m0 = blockIdx.x*64, d0 = blockIdx.y*64;
  const int tid = threadIdx.x;
  {
    int r = tid>>2, c = (tid&3)*16;
    const f16* p = in + (size_t)(m0+r)*C + d0 + c;
    *(f16x8*)&T[r][c]   = *(const f16x8*)p;
    *(f16x8*)&T[r][c+8] = *(const f16x8*)(p+8);
  }
  __syncthreads();
  {
    int dd = tid>>2, mq = (tid&3)*16;
    f16 v[16];
    #pragma unroll
    for (int e=0;e<16;++e) v[e] = T[mq+e][dd];
    f16* p = out + (size_t)(d0+dd)*R + m0 + mq;
    *(f16x8*)p     = *(f16x8*)&v[0];
    *(f16x8*)(p+8) = *(f16x8*)&v[8];
  }
}

// ---------- all weight casts/transposes in ONE kernel ----------
__global__ __launch_bounds__(256) void prep_k(
    const float* __restrict__ Wv,   const float* __restrict__ Wq_a,
    const float* __restrict__ Wk_a, const float* __restrict__ Wv_a,
    const float* __restrict__ Wo_a, const float* __restrict__ W1,
    const float* __restrict__ W2,   const float* __restrict__ Wk,
    const float* __restrict__ Wq,
    f16* __restrict__ WvT, f16* __restrict__ WqkvT, f16* __restrict__ WoaT,
    f16* __restrict__ W1T, f16* __restrict__ W2T,
    f16* __restrict__ Wkf, f16* __restrict__ Wqf)
{
  __shared__ float t[32][33];
  int bid = blockIdx.x;
  const float* src; f16* dst; int R, C; bool tr = true;
  if      (bid < 576)  {              src=Wv;   dst=WvT;             R=768;  C=768; }
  else if (bid < 960)  { bid-=576;    src=Wq_a; dst=WqkvT;           R=768;  C=512; }
  else if (bid < 1344) { bid-=960;    src=Wk_a; dst=WqkvT+512*768;   R=768;  C=512; }
  else if (bid < 1728) { bid-=1344;   src=Wv_a; dst=WqkvT+1024*768;  R=768;  C=512; }
  else if (bid < 2112) { bid-=1728;   src=Wo_a; dst=WoaT;            R=512;  C=768; }
  else if (bid < 6720) { bid-=2112;   src=W1;   dst=W1T;             R=768;  C=6144; }
  else if (bid < 9024) { bid-=6720;   src=W2;   dst=W2T;             R=3072; C=768; }
  else if (bid < 9600) { bid-=9024;   src=Wk;   dst=Wkf;             R=768;  C=768; tr=false; }
  else                 { bid-=9600;   src=Wq;   dst=Wqf;             R=768;  C=768; tr=false; }
  const int tpr = C/32;
  const int r0 = (bid / tpr)*32, c0 = (bid % tpr)*32;
  const int lc = threadIdx.x & 31, g8 = threadIdx.x >> 5;
  if (tr){
    #pragma unroll
    for (int s=0;s<4;++s){
      int r = g8*4 + s;
      t[r][lc] = src[(size_t)(r0+r)*C + c0+lc];
    }
    __syncthreads();
    #pragma unroll
    for (int s=0;s<4;++s){
      int c = g8*4 + s;
      dst[(size_t)(c0+c)*R + r0+lc] = (f16)t[lc][c];
    }
  } else {
    #pragma unroll
    for (int s=0;s<4;++s){
      int r = g8*4 + s;
      dst[(size_t)(r0+r)*C + c0+lc] = (f16)src[(size_t)(r0+r)*C + c0+lc];
    }
  }
}

// ---------- attn_map output (rowsum inline) ----------
__global__ __launch_bounds__(256) void attnout_k(
    const f16* __restrict__ attn, const float* __restrict__ rsPart,
    float* __restrict__ out)
{
  __shared__ float rsum[16];
  const int bid = blockIdx.x, tid = threadIdx.x;
  const int b = bid >> 6;
  if (tid < 16){
    float s = 0.f;
    #pragma unroll
    for (int jt=0;jt<16;++jt) s += rsPart[(size_t)((b*16+jt)<<4) + tid];
    rsum[tid] = s;
  }
  __syncthreads();
  int idx = bid*256 + tid;
  int i = idx & 15;
  int j = (idx >> 4) & 1023;
  out[idx] = (float)attn[((size_t)(b*NSLOT)+i)*NTOK + j] / rsum[i];
}

extern "C" void kernel_launch(void* const* d_in, const int* in_sizes, int n_in,
                              void* d_out, int out_size, void* d_ws, size_t ws_size,
                              hipStream_t stream) {
  const float* x        = (const float*)d_in[0];
  const float* noise    = (const float*)d_in[1];
  const float* init_mu  = (const float*)d_in[2];
  const float* init_ls  = (const float*)d_in[3];
  const float* Wk       = (const float*)d_in[4];
  const float* Wv       = (const float*)d_in[5];
  const float* Wq       = (const float*)d_in[6];
  const float* ni_g     = (const float*)d_in[7];
  const float* ni_b     = (const float*)d_in[8];
  const float* ns_g     = (const float*)d_in[9];
  const float* ns_b     = (const float*)d_in[10];
  const float* nica_g   = (const float*)d_in[11];
  const float* nica_b   = (const float*)d_in[12];
  const float* ln1_g    = (const float*)d_in[13];
  const float* ln1_b    = (const float*)d_in[14];
  const float* Wq_a     = (const float*)d_in[15];
  const float* Wk_a     = (const float*)d_in[16];
  const float* Wv_a     = (const float*)d_in[17];
  const float* Wo_a     = (const float*)d_in[18];
  const float* ln2_g    = (const float*)d_in[19];
  const float* ln2_b    = (const float*)d_in[20];
  const float* W1       = (const float*)d_in[21];
  const float* W2       = (const float*)d_in[22];
  const float* lnf_g    = (const float*)d_in[23];
  const float* lnf_b    = (const float*)d_in[24];

  char* w = (char*)d_ws;
  size_t off = 0;
  auto alloc = [&](size_t bytes)->char*{
    char* p = w + off; off += (bytes + 255) & ~(size_t)255; return p;
  };
  f16* xn_h  = (f16*)alloc((size_t)NTOT*D_DIM*2);
  f16* xnT_h = (f16*)alloc((size_t)D_DIM*NTOT*2);
  f16* Wkf   = (f16*)alloc((size_t)768*768*2);
  f16* Wqf   = (f16*)alloc((size_t)768*768*2);
  f16* BtQK  = (f16*)alloc((size_t)768*768*2);
  f16* WvT   = (f16*)alloc((size_t)768*768*2);
  f16* WqkvT = (f16*)alloc((size_t)1536*768*2);
  f16* WoaT  = (f16*)alloc((size_t)768*512*2);
  f16* W1T   = (f16*)alloc((size_t)6144*768*2);
  f16* W2T   = (f16*)alloc((size_t)768*3072*2);
  float* slots = (float*)alloc(512*768*4);
  float* hbuf  = (float*)alloc(512*768*4);
  float* accb  = (float*)alloc(512*768*4);
  f16* tmp_h  = (f16*)alloc(512*768*2);
  f16* tmp2_h = (f16*)alloc(512*768*2);
  f16* q_h    = (f16*)alloc(512*768*2);
  f16* qkv_h  = (f16*)alloc((size_t)512*1536*2);
  f16* act_h  = (f16*)alloc((size_t)512*3072*2);
  f16* attn_h = (f16*)alloc((size_t)NB*NSLOT*NTOK*2);
  float* rsPart = (float*)alloc((size_t)32*16*16*4);

  // weight prep: all casts/transposes in one launch
  prep_k<<<10176, 256, 0, stream>>>(Wv, Wq_a, Wk_a, Wv_a, Wo_a, W1, W2, Wk, Wq,
                                    WvT, WqkvT, WoaT, W1T, W2T, Wkf, Wqf);

  // BtQK[f][e] = sum_d Wk[f][d] * Wq[e][d]
  mgemm64_k<1><<<dim3(12, 12, 1), 256, 0, stream>>>(Wkf, Wqf, BtQK, 768, 768, 768, 768);

  // xn = LN(x); xnT = xn^T
  lnw_k<<<NTOT/4, 256, 0, stream>>>(x, ni_g, ni_b, xn_h);
  transp_k<<<dim3(NTOT/64, D_DIM/64), 256, 0, stream>>>(xn_h, xnT_h, NTOT, D_DIM);

  // slots = mu + exp(ls)*noise; accb = slots; tmp2 = LN(slots, ns)
  slotsinit_k<<<128, 256, 0, stream>>>(noise, init_mu, init_ls, ns_g, ns_b,
                                       slots, accb, tmp2_h);

  for (int it=0; it<4; ++it){
    // q_eff = LN(slots,ns) @ (Wq Wk^T)
    mgemm64_k<1><<<dim3(8, 12, 1), 256, 0, stream>>>(tmp2_h, BtQK, q_h, 512, 768, 768, 768);
    // dots = q_eff @ xn^T + inverted softmax
    dots_k<<<dim3(NB, 16), 256, 0, stream>>>(q_h, xn_h, attn_h, rsPart);
    // accb += (attn @ xn)/rowsum @ Wv   (fused t + upd, atomic split-K over d-tiles)
    attnv_k<<<dim3(NB, 12), 256, 0, stream>>>(attn_h, rsPart, xnT_h, WvT, accb);
    // hbuf = LN(accb, nica); tmp = LN(hbuf, ln1)
    lnlnw_k<false><<<128, 256, 0, stream>>>(accb, nica_g, nica_b, ln1_g, ln1_b,
                                            hbuf, tmp_h, nullptr);
    // qkv = a @ [Wq_a|Wk_a|Wv_a]
    mgemm64_k<1><<<dim3(8, 24, 1), 256, 0, stream>>>(tmp_h, WqkvT, qkv_h, 512, 1536, 768, 768);
    // hbuf += attn(qkv) @ Wo  (fused, atomic split-K over heads)
    encwo_k<<<dim3(NB, 8), 256, 0, stream>>>(qkv_h, qkv_h + 512, qkv_h + 1024, 1536,
                                             WoaT, hbuf);
    // f = LN(hbuf, ln2)
    lnw_k<<<128, 256, 0, stream>>>(hbuf, ln2_g, ln2_b, tmp_h);
    // act = glu(f @ W1)
    w1glu_k<<<dim3(8, 48), 256, 0, stream>>>(tmp_h, W1T, act_h, 512);
    // hbuf += act @ W2 (split-K=4 atomic)
    mgemm64_k<2><<<dim3(8, 12, 4), 256, 0, stream>>>(act_h, W2T, hbuf, 512, 768, 3072, 768);
    // slots = LN(hbuf, lnf); tmp2 = LN(slots, ns); accb = slots (for next iter's attnv)
    lnlnw_k<true><<<128, 256, 0, stream>>>(hbuf, lnf_g, lnf_b, ns_g, ns_b,
                                           slots, tmp2_h, accb);
  }

  hipMemcpyAsync(d_out, slots, (size_t)512*768*4, hipMemcpyDeviceToDevice, stream);
  attnout_k<<<NB*NTOK*NSLOT/256, 256, 0, stream>>>(attn_h, rsPart, (float*)d_out + 512*768);
}

// Round 2
// 693.847 us; speedup vs baseline: 1.0280x; 1.0280x over previous
//
#include <hip/hip_runtime.h>
#include <hip/hip_bf16.h>
#include <stdint.h>

typedef _Float16 f16;
typedef __attribute__((ext_vector_type(8))) _Float16 f16x8;
typedef __attribute__((ext_vector_type(4))) _Float16 f16x4;
typedef __attribute__((ext_vector_type(4))) float f32x4;

#define GLOBAL_AS __attribute__((address_space(1)))
#define LDS_AS __attribute__((address_space(3)))

#define D_DIM 768
#define NTOK 1024
#define NSLOT 16
#define NB 32
#define NTOT (NB*NTOK)   // 32768
#define HDIM 512
#define INNER 3072
#define SCALE_D 0.03608439182435161f   // 768^-0.5
#define SCALE_H 0.125f                 // 64^-0.5

// ---------- MFMA GEMM 64x64, BK=128 (4 panels), double-buffered counted-vmcnt pipeline ----------
// OUT: 0 = f32 store, 1 = f16 store.
template<int OUT>
__global__ __launch_bounds__(256) void mgemm64_k(
    const f16* __restrict__ A, const f16* __restrict__ Bt,
    void* __restrict__ Cout, int M, int N, int K, int nsteps)
{
  __shared__ __align__(16) f16 As[2][64*128];
  __shared__ __align__(16) f16 Bs[2][64*128];
  const int tid = threadIdx.x;
  const int lane = tid & 63;
  const int wave = tid >> 6;
  const int m0 = blockIdx.x*64, n0 = blockIdx.y*64;
  const int wm = (wave>>1)*32, wn = (wave&1)*32;
  const int quad = lane>>4, l16 = lane&15;

  const int sr = tid>>2;
  const int sc = (tid&3)*8;
  const f16* gA = A  + (size_t)(m0+sr)*K + sc;
  const f16* gB = Bt + (size_t)(n0+sr)*K + sc;

  f32x4 acc[2][2] = {};

  auto stage = [&](int t, int buf){
    LDS_AS f16* lA = (LDS_AS f16*)&As[buf][(size_t)tid*8];
    LDS_AS f16* lB = (LDS_AS f16*)&Bs[buf][(size_t)tid*8];
    const f16* pA = gA + t*128;
    const f16* pB = gB + t*128;
    #pragma unroll
    for (int p=0;p<4;++p){
      __builtin_amdgcn_global_load_lds((const GLOBAL_AS void*)(pA + p*32),
                                       (LDS_AS void*)(lA + (size_t)p*2048), 16, 0, 0);
      __builtin_amdgcn_global_load_lds((const GLOBAL_AS void*)(pB + p*32),
                                       (LDS_AS void*)(lB + (size_t)p*2048), 16, 0, 0);
    }
  };

  stage(0, 0);
  for (int t=0; t<nsteps; ++t){
    const int cur = t & 1;
    if (t+1 < nsteps){
      stage(t+1, cur^1);
      asm volatile("s_waitcnt vmcnt(8) lgkmcnt(0)" ::: "memory");
    } else {
      asm volatile("s_waitcnt vmcnt(0) lgkmcnt(0)" ::: "memory");
    }
    __builtin_amdgcn_s_barrier();
    __builtin_amdgcn_sched_barrier(0);
    const f16* fA0 = &As[cur][(wm + l16)*32 + quad*8];
    const f16* fB0 = &Bs[cur][(wn + l16)*32 + quad*8];
    #pragma unroll
    for (int p=0;p<4;++p){
      f16x8 a0 = *(const f16x8*)(fA0 + p*2048);
      f16x8 a1 = *(const f16x8*)(fA0 + p*2048 + 16*32);
      f16x8 b0 = *(const f16x8*)(fB0 + p*2048);
      f16x8 b1 = *(const f16x8*)(fB0 + p*2048 + 16*32);
      acc[0][0] = __builtin_amdgcn_mfma_f32_16x16x32_f16(a0,b0,acc[0][0],0,0,0);
      acc[0][1] = __builtin_amdgcn_mfma_f32_16x16x32_f16(a0,b1,acc[0][1],0,0,0);
      acc[1][0] = __builtin_amdgcn_mfma_f32_16x16x32_f16(a1,b0,acc[1][0],0,0,0);
      acc[1][1] = __builtin_amdgcn_mfma_f32_16x16x32_f16(a1,b1,acc[1][1],0,0,0);
    }
    __builtin_amdgcn_sched_barrier(0);
    __builtin_amdgcn_s_barrier();
  }
  #pragma unroll
  for (int mt=0;mt<2;++mt){
    #pragma unroll
    for (int nt=0;nt<2;++nt){
      int gm = m0 + wm + mt*16 + quad*4;
      int gn = n0 + wn + nt*16 + l16;
      #pragma unroll
      for (int r=0;r<4;++r){
        float c = acc[mt][nt][r];
        size_t idx = (size_t)(gm+r)*N + gn;
        if (OUT==1) ((f16*)Cout)[idx] = (f16)c;
        else        ((float*)Cout)[idx] = c;
      }
    }
  }
}

// ---------- W1 + GLU fused, pipelined ----------
__global__ __launch_bounds__(256) void w1glu_k(
    const f16* __restrict__ A, const f16* __restrict__ W1T,
    f16* __restrict__ act, int M)
{
  __shared__ __align__(16) f16 As[2][64*128];
  __shared__ __align__(16) f16 Bu[2][64*128];
  __shared__ __align__(16) f16 Bg[2][64*128];
  const int K = 768;
  const int tid = threadIdx.x;
  const int lane = tid & 63;
  const int wave = tid >> 6;
  const int m0 = blockIdx.x*64, n0 = blockIdx.y*64;
  const int wm = (wave>>1)*32, wn = (wave&1)*32;
  const int quad = lane>>4, l16 = lane&15;

  const int sr = tid>>2;
  const int sc = (tid&3)*8;
  const f16* gA  = A   + (size_t)(m0+sr)*K + sc;
  const f16* gBu = W1T + (size_t)(n0+sr)*K + sc;
  const f16* gBg = W1T + (size_t)(3072+n0+sr)*K + sc;

  f32x4 accU[2][2] = {};
  f32x4 accG[2][2] = {};

  auto stage = [&](int t, int buf){
    LDS_AS f16* lA  = (LDS_AS f16*)&As[buf][(size_t)tid*8];
    LDS_AS f16* lBu = (LDS_AS f16*)&Bu[buf][(size_t)tid*8];
    LDS_AS f16* lBg = (LDS_AS f16*)&Bg[buf][(size_t)tid*8];
    #pragma unroll
    for (int p=0;p<4;++p){
      __builtin_amdgcn_global_load_lds((const GLOBAL_AS void*)(gA  + t*128 + p*32),
                                       (LDS_AS void*)(lA  + (size_t)p*2048), 16, 0, 0);
      __builtin_amdgcn_global_load_lds((const GLOBAL_AS void*)(gBu + t*128 + p*32),
                                       (LDS_AS void*)(lBu + (size_t)p*2048), 16, 0, 0);
      __builtin_amdgcn_global_load_lds((const GLOBAL_AS void*)(gBg + t*128 + p*32),
                                       (LDS_AS void*)(lBg + (size_t)p*2048), 16, 0, 0);
    }
  };

  stage(0, 0);
  for (int t=0; t<6; ++t){
    const int cur = t & 1;
    if (t+1 < 6){
      stage(t+1, cur^1);
      asm volatile("s_waitcnt vmcnt(12) lgkmcnt(0)" ::: "memory");
    } else {
      asm volatile("s_waitcnt vmcnt(0) lgkmcnt(0)" ::: "memory");
    }
    __builtin_amdgcn_s_barrier();
    __builtin_amdgcn_sched_barrier(0);
    const f16* fA0 = &As[cur][(wm + l16)*32 + quad*8];
    const f16* fU0 = &Bu[cur][(wn + l16)*32 + quad*8];
    const f16* fG0 = &Bg[cur][(wn + l16)*32 + quad*8];
    #pragma unroll
    for (int p=0;p<4;++p){
      f16x8 a0 = *(const f16x8*)(fA0 + p*2048);
      f16x8 a1 = *(const f16x8*)(fA0 + p*2048 + 16*32);
      f16x8 u0 = *(const f16x8*)(fU0 + p*2048);
      f16x8 u1 = *(const f16x8*)(fU0 + p*2048 + 16*32);
      f16x8 g0 = *(const f16x8*)(fG0 + p*2048);
      f16x8 g1 = *(const f16x8*)(fG0 + p*2048 + 16*32);
      accU[0][0] = __builtin_amdgcn_mfma_f32_16x16x32_f16(a0,u0,accU[0][0],0,0,0);
      accU[0][1] = __builtin_amdgcn_mfma_f32_16x16x32_f16(a0,u1,accU[0][1],0,0,0);
      accU[1][0] = __builtin_amdgcn_mfma_f32_16x16x32_f16(a1,u0,accU[1][0],0,0,0);
      accU[1][1] = __builtin_amdgcn_mfma_f32_16x16x32_f16(a1,u1,accU[1][1],0,0,0);
      accG[0][0] = __builtin_amdgcn_mfma_f32_16x16x32_f16(a0,g0,accG[0][0],0,0,0);
      accG[0][1] = __builtin_amdgcn_mfma_f32_16x16x32_f16(a0,g1,accG[0][1],0,0,0);
      accG[1][0] = __builtin_amdgcn_mfma_f32_16x16x32_f16(a1,g0,accG[1][0],0,0,0);
      accG[1][1] = __builtin_amdgcn_mfma_f32_16x16x32_f16(a1,g1,accG[1][1],0,0,0);
    }
    __builtin_amdgcn_sched_barrier(0);
    __builtin_amdgcn_s_barrier();
  }
  #pragma unroll
  for (int mt=0;mt<2;++mt){
    #pragma unroll
    for (int nt=0;nt<2;++nt){
      int gm = m0 + wm + mt*16 + quad*4;
      int gn = n0 + wn + nt*16 + l16;
      #pragma unroll
      for (int r=0;r<4;++r){
        float u = accU[mt][nt][r];
        float g = accG[mt][nt][r];
        float sg = g / (1.0f + __expf(-g));
        act[(size_t)(gm+r)*INNER + gn] = (f16)(u*sg);
      }
    }
  }
}

// ---------- MFMA dots (q_eff @ xn^T) + inverted softmax + EPS + partial rowsum, pipelined ----------
__global__ __launch_bounds__(256) void dots_k(
    const f16* __restrict__ Q,    // [32,16,768] q_eff
    const f16* __restrict__ Xn,   // [32768,768]
    f16* __restrict__ attn,       // [32,16,1024] f16
    float* __restrict__ rsPart)   // [32][16 jt][16 i]
{
  __shared__ __align__(16) f16 qf[16*768];    // 24 KB
  __shared__ __align__(16) f16 ks[2][64*128]; // 2x16 KB
  __shared__ float rpart[4][16];
  const int b = blockIdx.x, jt = blockIdx.y;
  const int tid = threadIdx.x;
  const int lane = tid & 63;
  const int w = tid >> 6;
  const int quad = lane>>4, l16 = lane&15;

  #pragma unroll
  for (int c=0;c<6;++c){
    int p = c*256 + tid;
    int ki = p >> 6, qd = (p >> 4) & 3, rw = p & 15;
    f16x8 v = *(const f16x8*)(Q + ((size_t)(b*NSLOT+rw))*D_DIM + ki*32 + qd*8);
    *(f16x8*)&qf[(size_t)p*8] = v;
  }

  const f16* gK = Xn + ((size_t)(b*NTOK + jt*64 + (tid>>2)))*D_DIM + (tid&3)*8;
  auto stage = [&](int t, int buf){
    LDS_AS f16* lK = (LDS_AS f16*)&ks[buf][(size_t)tid*8];
    #pragma unroll
    for (int p=0;p<4;++p)
      __builtin_amdgcn_global_load_lds((const GLOBAL_AS void*)(gK + t*128 + p*32),
                                       (LDS_AS void*)(lK + (size_t)p*2048), 16, 0, 0);
  };

  stage(0, 0);
  __syncthreads();   // qf visible; stage0 drained (prologue only)

  f32x4 acc = {};
  for (int it=0; it<6; ++it){
    const int cur = it & 1;
    if (it+1 < 6){
      stage(it+1, cur^1);
      asm volatile("s_waitcnt vmcnt(4) lgkmcnt(0)" ::: "memory");
    } else {
      asm volatile("s_waitcnt vmcnt(0) lgkmcnt(0)" ::: "memory");
    }
    __builtin_amdgcn_s_barrier();
    __builtin_amdgcn_sched_barrier(0);
    #pragma unroll
    for (int p=0;p<4;++p){
      f16x8 a  = *(const f16x8*)&qf[(((size_t)(it*4+p)*4 + quad)*16 + l16)*8];
      f16x8 bf = *(const f16x8*)&ks[cur][(size_t)p*2048 + (w*16+l16)*32 + quad*8];
      acc = __builtin_amdgcn_mfma_f32_16x16x32_f16(a, bf, acc, 0, 0, 0);
    }
    __builtin_amdgcn_sched_barrier(0);
    __builtin_amdgcn_s_barrier();
  }

  float v0 = acc[0]*SCALE_D, v1 = acc[1]*SCALE_D, v2 = acc[2]*SCALE_D, v3 = acc[3]*SCALE_D;
  float mx = fmaxf(fmaxf(v0,v1), fmaxf(v2,v3));
  mx = fmaxf(mx, __shfl_xor(mx, 16));
  mx = fmaxf(mx, __shfl_xor(mx, 32));
  float e0 = __expf(v0-mx), e1 = __expf(v1-mx), e2 = __expf(v2-mx), e3 = __expf(v3-mx);
  float s = e0+e1+e2+e3;
  s += __shfl_xor(s, 16);
  s += __shfl_xor(s, 32);
  float inv = 1.0f/s;
  float a0 = e0*inv + 1e-8f, a1 = e1*inv + 1e-8f, a2 = e2*inv + 1e-8f, a3 = e3*inv + 1e-8f;

  int jcol = jt*64 + w*16 + l16;
  int ibase = b*NSLOT + quad*4;
  attn[(size_t)(ibase+0)*NTOK + jcol] = (f16)a0;
  attn[(size_t)(ibase+1)*NTOK + jcol] = (f16)a1;
  attn[(size_t)(ibase+2)*NTOK + jcol] = (f16)a2;
  attn[(size_t)(ibase+3)*NTOK + jcol] = (f16)a3;

  float t0=a0, t1=a1, t2=a2, t3=a3;
  #pragma unroll
  for (int m=1;m<16;m<<=1){
    t0 += __shfl_xor(t0, m);
    t1 += __shfl_xor(t1, m);
    t2 += __shfl_xor(t2, m);
    t3 += __shfl_xor(t3, m);
  }
  if (l16 == 0){
    rpart[w][quad*4+0] = t0;
    rpart[w][quad*4+1] = t1;
    rpart[w][quad*4+2] = t2;
    rpart[w][quad*4+3] = t3;
  }
  __syncthreads();
  if (tid < 16){
    float ss = rpart[0][tid] + rpart[1][tid] + rpart[2][tid] + rpart[3][tid];
    rsPart[(size_t)((b*16 + jt)<<4) + tid] = ss;
  }
}

// ---------- t = (attn @ xn) / rowsum via MFMA on xnT, pipelined ----------
__global__ __launch_bounds__(256) void attnv_k(
    const f16* __restrict__ attn,   // [32,16,1024] f16
    const float* __restrict__ rsPart,
    const f16* __restrict__ XnT,    // [768, 32768]
    f16* __restrict__ t_out)        // [32,16,768] f16
{
  __shared__ __align__(16) f16 Asl[2][16*128];
  __shared__ __align__(16) f16 Bsl[2][64*128];
  __shared__ float rsum[16];
  const int b = blockIdx.x, d0 = blockIdx.y*64;
  const int tid = threadIdx.x;
  const int lane = tid & 63;
  const int w = tid >> 6;
  const int quad = lane>>4, l16 = lane&15;

  if (tid < 16){
    float s = 0.f;
    #pragma unroll
    for (int jt=0;jt<16;++jt) s += rsPart[(size_t)((b*16 + jt)<<4) + tid];
    rsum[tid] = s;
  }

  const int pa = tid>>6, ta = tid&63;
  const f16* gA = attn + ((size_t)(b*NSLOT + (ta>>2)))*NTOK + pa*32 + (ta&3)*8;
  const f16* gB = XnT + ((size_t)(d0 + (tid>>2)))*NTOT + b*NTOK + (tid&3)*8;

  auto stage = [&](int t, int buf){
    LDS_AS f16* lA = (LDS_AS f16*)&Asl[buf][(size_t)pa*512 + ta*8];
    LDS_AS f16* lB = (LDS_AS f16*)&Bsl[buf][(size_t)tid*8];
    __builtin_amdgcn_global_load_lds((const GLOBAL_AS void*)(gA + t*128),
                                     (LDS_AS void*)lA, 16, 0, 0);
    #pragma unroll
    for (int p=0;p<4;++p)
      __builtin_amdgcn_global_load_lds((const GLOBAL_AS void*)(gB + t*128 + p*32),
                                       (LDS_AS void*)(lB + (size_t)p*2048), 16, 0, 0);
  };

  stage(0, 0);
  f32x4 acc = {};
  for (int it=0; it<8; ++it){
    const int cur = it & 1;
    if (it+1 < 8){
      stage(it+1, cur^1);
      asm volatile("s_waitcnt vmcnt(5) lgkmcnt(0)" ::: "memory");
    } else {
      asm volatile("s_waitcnt vmcnt(0) lgkmcnt(0)" ::: "memory");
    }
    __builtin_amdgcn_s_barrier();
    __builtin_amdgcn_sched_barrier(0);
    #pragma unroll
    for (int p=0;p<4;++p){
      f16x8 a  = *(const f16x8*)&Asl[cur][(size_t)p*512 + l16*32 + quad*8];
      f16x8 bf = *(const f16x8*)&Bsl[cur][(size_t)p*2048 + (w*16+l16)*32 + quad*8];
      acc = __builtin_amdgcn_mfma_f32_16x16x32_f16(a, bf, acc, 0, 0, 0);
    }
    __builtin_amdgcn_sched_barrier(0);
    __builtin_amdgcn_s_barrier();
  }
  int dcol = d0 + w*16 + l16;
  #pragma unroll
  for (int r=0;r<4;++r){
    int i = quad*4 + r;
    t_out[(size_t)(b*NSLOT + i)*D_DIM + dcol] = (f16)(acc[r] / rsum[i]);
  }
}

// ---------- wave-per-row LN (4 rows/block), f16 out ----------
__global__ __launch_bounds__(256) void lnw_k(
    const float* __restrict__ X,
    const float* __restrict__ g, const float* __restrict__ bb,
    f16* __restrict__ out)
{
  const int lane = threadIdx.x & 63;
  const size_t row = (size_t)blockIdx.x*4 + (threadIdx.x>>6);
  const float* x = X + row*D_DIM;
  float4 v[3]; float s=0.f, ss=0.f;
  #pragma unroll
  for (int t=0;t<3;++t){
    v[t] = *(const float4*)(x + lane*4 + t*256);
    s  += v[t].x+v[t].y+v[t].z+v[t].w;
    ss += v[t].x*v[t].x+v[t].y*v[t].y+v[t].z*v[t].z+v[t].w*v[t].w;
  }
  #pragma unroll
  for (int m=1;m<64;m<<=1){ s += __shfl_xor(s,m); ss += __shfl_xor(ss,m); }
  float mean = s*(1.0f/768.0f);
  float inv  = rsqrtf(ss*(1.0f/768.0f) - mean*mean + 1e-5f);
  #pragma unroll
  for (int t=0;t<3;++t){
    int c0 = lane*4 + t*256;
    float4 gg = *(const float4*)(g + c0);
    float4 bv = *(const float4*)(bb + c0);
    f16x4 h4;
    h4.x = (f16)((v[t].x-mean)*inv*gg.x + bv.x);
    h4.y = (f16)((v[t].y-mean)*inv*gg.y + bv.y);
    h4.z = (f16)((v[t].z-mean)*inv*gg.z + bv.z);
    h4.w = (f16)((v[t].w-mean)*inv*gg.w + bv.w);
    *(f16x4*)(out + row*D_DIM + c0) = h4;
  }
}

// ---------- sum2 -> writeback + LN(f16): X = X+X2 (stored); out = LN(X+X2) ----------
__global__ __launch_bounds__(256) void lnaddwb_k(
    float* __restrict__ X, const float* __restrict__ X2,
    const float* __restrict__ g, const float* __restrict__ bb,
    f16* __restrict__ out)
{
  const int lane = threadIdx.x & 63;
  const size_t row = (size_t)blockIdx.x*4 + (threadIdx.x>>6);
  float* x = X + row*D_DIM;
  const float* x2 = X2 + row*D_DIM;
  float4 v[3]; float s=0.f, ss=0.f;
  #pragma unroll
  for (int t=0;t<3;++t){
    int c0 = lane*4 + t*256;
    float4 a = *(const float4*)(x + c0);
    float4 b = *(const float4*)(x2 + c0);
    v[t].x = a.x+b.x; v[t].y = a.y+b.y; v[t].z = a.z+b.z; v[t].w = a.w+b.w;
    *(float4*)(x + c0) = v[t];
    s  += v[t].x+v[t].y+v[t].z+v[t].w;
    ss += v[t].x*v[t].x+v[t].y*v[t].y+v[t].z*v[t].z+v[t].w*v[t].w;
  }
  #pragma unroll
  for (int m=1;m<64;m<<=1){ s += __shfl_xor(s,m); ss += __shfl_xor(ss,m); }
  float mean = s*(1.0f/768.0f);
  float inv  = rsqrtf(ss*(1.0f/768.0f) - mean*mean + 1e-5f);
  #pragma unroll
  for (int t=0;t<3;++t){
    int c0 = lane*4 + t*256;
    float4 gg = *(const float4*)(g + c0);
    float4 bv = *(const float4*)(bb + c0);
    f16x4 h4;
    h4.x = (f16)((v[t].x-mean)*inv*gg.x + bv.x);
    h4.y = (f16)((v[t].y-mean)*inv*gg.y + bv.y);
    h4.z = (f16)((v[t].z-mean)*inv*gg.z + bv.z);
    h4.w = (f16)((v[t].w-mean)*inv*gg.w + bv.w);
    *(f16x4*)(out + row*D_DIM + c0) = h4;
  }
}

// ---------- wave-per-row double LN with add: out1=LN(X+X2,g1,b1) f32, out2=LN(out1,g2,b2) f16 ----------
__global__ __launch_bounds__(256) void lnlnw_k(
    const float* __restrict__ X, const float* __restrict__ X2,
    const float* __restrict__ g1, const float* __restrict__ b1,
    const float* __restrict__ g2, const float* __restrict__ b2,
    float* __restrict__ out1, f16* __restrict__ out2)
{
  const int lane = threadIdx.x & 63;
  const size_t row = (size_t)blockIdx.x*4 + (threadIdx.x>>6);
  const float* x = X + row*D_DIM;
  const float* x2 = X2 + row*D_DIM;
  float4 v[3]; float s=0.f, ss=0.f;
  #pragma unroll
  for (int t=0;t<3;++t){
    int c0 = lane*4 + t*256;
    float4 a = *(const float4*)(x + c0);
    float4 b = *(const float4*)(x2 + c0);
    v[t].x = a.x+b.x; v[t].y = a.y+b.y; v[t].z = a.z+b.z; v[t].w = a.w+b.w;
    s  += v[t].x+v[t].y+v[t].z+v[t].w;
    ss += v[t].x*v[t].x+v[t].y*v[t].y+v[t].z*v[t].z+v[t].w*v[t].w;
  }
  #pragma unroll
  for (int m=1;m<64;m<<=1){ s += __shfl_xor(s,m); ss += __shfl_xor(ss,m); }
  float mean = s*(1.0f/768.0f);
  float inv  = rsqrtf(ss*(1.0f/768.0f) - mean*mean + 1e-5f);
  float y[3][4]; float s2=0.f, ss2=0.f;
  #pragma unroll
  for (int t=0;t<3;++t){
    int c0 = lane*4 + t*256;
    float4 gg = *(const float4*)(g1 + c0);
    float4 bv = *(const float4*)(b1 + c0);
    y[t][0] = (v[t].x-mean)*inv*gg.x + bv.x;
    y[t][1] = (v[t].y-mean)*inv*gg.y + bv.y;
    y[t][2] = (v[t].z-mean)*inv*gg.z + bv.z;
    y[t][3] = (v[t].w-mean)*inv*gg.w + bv.w;
    float4 o = { y[t][0], y[t][1], y[t][2], y[t][3] };
    *(float4*)(out1 + row*D_DIM + c0) = o;
    s2  += y[t][0]+y[t][1]+y[t][2]+y[t][3];
    ss2 += y[t][0]*y[t][0]+y[t][1]*y[t][1]+y[t][2]*y[t][2]+y[t][3]*y[t][3];
  }
  #pragma unroll
  for (int m=1;m<64;m<<=1){ s2 += __shfl_xor(s2,m); ss2 += __shfl_xor(ss2,m); }
  float mean2 = s2*(1.0f/768.0f);
  float inv2  = rsqrtf(ss2*(1.0f/768.0f) - mean2*mean2 + 1e-5f);
  #pragma unroll
  for (int t=0;t<3;++t){
    int c0 = lane*4 + t*256;
    float4 gg = *(const float4*)(g2 + c0);
    float4 bv = *(const float4*)(b2 + c0);
    f16x4 h4;
    h4.x = (f16)((y[t][0]-mean2)*inv2*gg.x + bv.x);
    h4.y = (f16)((y[t][1]-mean2)*inv2*gg.y + bv.y);
    h4.z = (f16)((y[t][2]-mean2)*inv2*gg.z + bv.z);
    h4.w = (f16)((y[t][3]-mean2)*inv2*gg.w + bv.w);
    *(f16x4*)(out2 + row*D_DIM + c0) = h4;
  }
}

// ---------- slots init + LN(ns) fused ----------
__global__ __launch_bounds__(256) void slotsinit_k(
    const float* __restrict__ noise, const float* __restrict__ mu,
    const float* __restrict__ ls,
    const float* __restrict__ nsg, const float* __restrict__ nsb,
    float* __restrict__ slots, f16* __restrict__ tmp2)
{
  const int lane = threadIdx.x & 63;
  const size_t row = (size_t)blockIdx.x*4 + (threadIdx.x>>6);
  float4 v[3]; float s=0.f, ss=0.f;
  #pragma unroll
  for (int t=0;t<3;++t){
    int c0 = lane*4 + t*256;
    float4 nz = *(const float4*)(noise + row*D_DIM + c0);
    float4 m4 = *(const float4*)(mu + c0);
    float4 l4 = *(const float4*)(ls + c0);
    v[t].x = m4.x + __expf(l4.x)*nz.x;
    v[t].y = m4.y + __expf(l4.y)*nz.y;
    v[t].z = m4.z + __expf(l4.z)*nz.z;
    v[t].w = m4.w + __expf(l4.w)*nz.w;
    *(float4*)(slots + row*D_DIM + c0) = v[t];
    s  += v[t].x+v[t].y+v[t].z+v[t].w;
    ss += v[t].x*v[t].x+v[t].y*v[t].y+v[t].z*v[t].z+v[t].w*v[t].w;
  }
  #pragma unroll
  for (int m=1;m<64;m<<=1){ s += __shfl_xor(s,m); ss += __shfl_xor(ss,m); }
  float mean = s*(1.0f/768.0f);
  float inv  = rsqrtf(ss*(1.0f/768.0f) - mean*mean + 1e-5f);
  #pragma unroll
  for (int t=0;t<3;++t){
    int c0 = lane*4 + t*256;
    float4 gg = *(const float4*)(nsg + c0);
    float4 bv = *(const float4*)(nsb + c0);
    f16x4 h4;
    h4.x = (f16)((v[t].x-mean)*inv*gg.x + bv.x);
    h4.y = (f16)((v[t].y-mean)*inv*gg.y + bv.y);
    h4.z = (f16)((v[t].z-mean)*inv*gg.z + bv.z);
    h4.w = (f16)((v[t].w-mean)*inv*gg.w + bv.w);
    *(f16x4*)(tmp2 + row*D_DIM + c0) = h4;
  }
}

// ---------- encoder self-attention ----------
__global__ __launch_bounds__(256) void encattn_k(
    const f16* __restrict__ QA, const f16* __restrict__ KA,
    const f16* __restrict__ VA, int QSTR,
    f16* __restrict__ O)
{
  __shared__ float qs[16][68], ks[16][68], vs[16][68], ps[16][20];
  const int b = blockIdx.x, h = blockIdx.y;
  const int tid = threadIdx.x;
  {
    int i = tid>>4, dd=(tid&15)*4;
    size_t base = ((size_t)(b*NSLOT+i))*QSTR + h*64 + dd;
    f16x4 uq = *(const f16x4*)(QA + base);
    f16x4 uk = *(const f16x4*)(KA + base);
    f16x4 uv = *(const f16x4*)(VA + base);
    float4 fq = { (float)uq.x, (float)uq.y, (float)uq.z, (float)uq.w };
    float4 fk = { (float)uk.x, (float)uk.y, (float)uk.z, (float)uk.w };
    float4 fv = { (float)uv.x, (float)uv.y, (float)uv.z, (float)uv.w };
    *(float4*)&qs[i][dd]=fq; *(float4*)&ks[i][dd]=fk; *(float4*)&vs[i][dd]=fv;
  }
  __syncthreads();
  {
    int i = tid>>4, j = tid&15;
    float s=0.f;
    #pragma unroll 8
    for (int d=0; d<64; ++d) s += qs[i][d]*ks[j][d];
    ps[i][j] = s*SCALE_H;
  }
  __syncthreads();
  if (tid < 16){
    int i = tid;
    float mx=-1e30f;
    #pragma unroll
    for (int j=0;j<16;++j) mx = fmaxf(mx, ps[i][j]);
    float sm=0.f;
    #pragma unroll
    for (int j=0;j<16;++j){ float e=__expf(ps[i][j]-mx); ps[i][j]=e; sm+=e; }
    float inv=1.0f/sm;
    #pragma unroll
    for (int j=0;j<16;++j) ps[i][j]*=inv;
  }
  __syncthreads();
  {
    int i = tid>>4, dq=(tid&15)*4;
    float a0=0,a1=0,a2=0,a3=0;
    #pragma unroll
    for (int j=0;j<16;++j){
      float p = ps[i][j];
      a0+=p*vs[j][dq+0]; a1+=p*vs[j][dq+1]; a2+=p*vs[j][dq+2]; a3+=p*vs[j][dq+3];
    }
    size_t base = ((size_t)(b*NSLOT+i))*HDIM + h*64 + dq;
    O[base+0]=(f16)a0; O[base+1]=(f16)a1; O[base+2]=(f16)a2; O[base+3]=(f16)a3;
  }
}

// ---------- f16 transpose: out[C][R] = in[R][C] ----------
__global__ __launch_bounds__(256) void transp_k(
    const f16* __restrict__ in, f16* __restrict__ out, int R, int C)
{
  __shared__ f16 T[64][72];
  const int m0 = blockIdx.x*64, d0 = blockIdx.y*64;
  const int tid = threadIdx.x;
  {
    int r = tid>>2, c = (tid&3)*16;
    const f16* p = in + (size_t)(m0+r)*C + d0 + c;
    *(f16x8*)&T[r][c]   = *(const f16x8*)p;
    *(f16x8*)&T[r][c+8] = *(const f16x8*)(p+8);
  }
  __syncthreads();
  {
    int dd = tid>>2, mq = (tid&3)*16;
    f16 v[16];
    #pragma unroll
    for (int e=0;e<16;++e) v[e] = T[mq+e][dd];
    f16* p = out + (size_t)(d0+dd)*R + m0 + mq;
    *(f16x8*)p     = *(f16x8*)&v[0];
    *(f16x8*)(p+8) = *(f16x8*)&v[8];
  }
}

// ---------- all weight casts/transposes in ONE kernel ----------
__global__ __launch_bounds__(256) void prep_k(
    const float* __restrict__ Wv,   const float* __restrict__ Wq_a,
    const float* __restrict__ Wk_a, const float* __restrict__ Wv_a,
    const float* __restrict__ Wo_a, const float* __restrict__ W1,
    const float* __restrict__ W2,   const float* __restrict__ Wk,
    const float* __restrict__ Wq,
    f16* __restrict__ WvT, f16* __restrict__ WqkvT, f16* __restrict__ WoaT,
    f16* __restrict__ W1T, f16* __restrict__ W2T,
    f16* __restrict__ Wkf, f16* __restrict__ Wqf)
{
  __shared__ float t[32][33];
  int bid = blockIdx.x;
  const float* src; f16* dst; int R, C; bool tr = true;
  if      (bid < 576)  {              src=Wv;   dst=WvT;             R=768;  C=768; }
  else if (bid < 960)  { bid-=576;    src=Wq_a; dst=WqkvT;           R=768;  C=512; }
  else if (bid < 1344) { bid-=960;    src=Wk_a; dst=WqkvT+512*768;   R=768;  C=512; }
  else if (bid < 1728) { bid-=1344;   src=Wv_a; dst=WqkvT+1024*768;  R=768;  C=512; }
  else if (bid < 2112) { bid-=1728;   src=Wo_a; dst=WoaT;            R=512;  C=768; }
  else if (bid < 6720) { bid-=2112;   src=W1;   dst=W1T;             R=768;  C=6144; }
  else if (bid < 9024) { bid-=6720;   src=W2;   dst=W2T;             R=3072; C=768; }
  else if (bid < 9600) { bid-=9024;   src=Wk;   dst=Wkf;             R=768;  C=768; tr=false; }
  else                 { bid-=9600;   src=Wq;   dst=Wqf;             R=768;  C=768; tr=false; }
  const int tpr = C/32;
  const int r0 = (bid / tpr)*32, c0 = (bid % tpr)*32;
  const int lc = threadIdx.x & 31, g8 = threadIdx.x >> 5;
  if (tr){
    #pragma unroll
    for (int s=0;s<4;++s){
      int r = g8*4 + s;
      t[r][lc] = src[(size_t)(r0+r)*C + c0+lc];
    }
    __syncthreads();
    #pragma unroll
    for (int s=0;s<4;++s){
      int c = g8*4 + s;
      dst[(size_t)(c0+c)*R + r0+lc] = (f16)t[lc][c];
    }
  } else {
    #pragma unroll
    for (int s=0;s<4;++s){
      int r = g8*4 + s;
      dst[(size_t)(r0+r)*C + c0+lc] = (f16)src[(size_t)(r0+r)*C + c0+lc];
    }
  }
}

// ---------- attn_map output (rowsum inline) ----------
__global__ __launch_bounds__(256) void attnout_k(
    const f16* __restrict__ attn, const float* __restrict__ rsPart,
    float* __restrict__ out)
{
  __shared__ float rsum[16];
  const int bid = blockIdx.x, tid = threadIdx.x;
  const int b = bid >> 6;
  if (tid < 16){
    float s = 0.f;
    #pragma unroll
    for (int jt=0;jt<16;++jt) s += rsPart[(size_t)((b*16+jt)<<4) + tid];
    rsum[tid] = s;
  }
  __syncthreads();
  int idx = bid*256 + tid;
  int i = idx & 15;
  int j = (idx >> 4) & 1023;
  out[idx] = (float)attn[((size_t)(b*NSLOT)+i)*NTOK + j] / rsum[i];
}

extern "C" void kernel_launch(void* const* d_in, const int* in_sizes, int n_in,
                              void* d_out, int out_size, void* d_ws, size_t ws_size,
                              hipStream_t stream) {
  const float* x        = (const float*)d_in[0];
  const float* noise    = (const float*)d_in[1];
  const float* init_mu  = (const float*)d_in[2];
  const float* init_ls  = (const float*)d_in[3];
  const float* Wk       = (const float*)d_in[4];
  const float* Wv       = (const float*)d_in[5];
  const float* Wq       = (const float*)d_in[6];
  const float* ni_g     = (const float*)d_in[7];
  const float* ni_b     = (const float*)d_in[8];
  const float* ns_g     = (const float*)d_in[9];
  const float* ns_b     = (const float*)d_in[10];
  const float* nica_g   = (const float*)d_in[11];
  const float* nica_b   = (const float*)d_in[12];
  const float* ln1_g    = (const float*)d_in[13];
  const float* ln1_b    = (const float*)d_in[14];
  const float* Wq_a     = (const float*)d_in[15];
  const float* Wk_a     = (const float*)d_in[16];
  const float* Wv_a     = (const float*)d_in[17];
  const float* Wo_a     = (const float*)d_in[18];
  const float* ln2_g    = (const float*)d_in[19];
  const float* ln2_b    = (const float*)d_in[20];
  const float* W1       = (const float*)d_in[21];
  const float* W2       = (const float*)d_in[22];
  const float* lnf_g    = (const float*)d_in[23];
  const float* lnf_b    = (const float*)d_in[24];

  char* w = (char*)d_ws;
  size_t off = 0;
  auto alloc = [&](size_t bytes)->char*{
    char* p = w + off; off += (bytes + 255) & ~(size_t)255; return p;
  };
  f16* xn_h  = (f16*)alloc((size_t)NTOT*D_DIM*2);
  f16* xnT_h = (f16*)alloc((size_t)D_DIM*NTOT*2);
  f16* Wkf   = (f16*)alloc((size_t)768*768*2);
  f16* Wqf   = (f16*)alloc((size_t)768*768*2);
  f16* BtQK  = (f16*)alloc((size_t)768*768*2);
  f16* WvT   = (f16*)alloc((size_t)768*768*2);
  f16* WqkvT = (f16*)alloc((size_t)1536*768*2);
  f16* WoaT  = (f16*)alloc((size_t)768*512*2);
  f16* W1T   = (f16*)alloc((size_t)6144*768*2);
  f16* W2T   = (f16*)alloc((size_t)768*3072*2);
  float* slots = (float*)alloc(512*768*4);
  float* hbuf  = (float*)alloc(512*768*4);
  float* upd   = (float*)alloc(512*768*4);
  float* obuf  = (float*)alloc(512*768*4);
  float* w2out = (float*)alloc(512*768*4);
  f16* tmp_h  = (f16*)alloc(512*768*2);
  f16* tmp2_h = (f16*)alloc(512*768*2);
  f16* q_h    = (f16*)alloc(512*768*2);
  f16* t_h    = (f16*)alloc(512*768*2);
  f16* qkv_h  = (f16*)alloc((size_t)512*1536*2);
  f16* o_h    = (f16*)alloc(512*512*2);
  f16* act_h  = (f16*)alloc((size_t)512*3072*2);
  f16* attn_h = (f16*)alloc((size_t)NB*NSLOT*NTOK*2);
  float* rsPart = (float*)alloc((size_t)32*16*16*4);

  // weight prep: all casts/transposes in one launch
  prep_k<<<10176, 256, 0, stream>>>(Wv, Wq_a, Wk_a, Wv_a, Wo_a, W1, W2, Wk, Wq,
                                    WvT, WqkvT, WoaT, W1T, W2T, Wkf, Wqf);

  // BtQK[f][e] = sum_d Wk[f][d] * Wq[e][d]
  mgemm64_k<1><<<dim3(12, 12), 256, 0, stream>>>(Wkf, Wqf, BtQK, 768, 768, 768, 6);

  // xn = LN(x); xnT = xn^T
  lnw_k<<<NTOT/4, 256, 0, stream>>>(x, ni_g, ni_b, xn_h);
  transp_k<<<dim3(NTOT/64, D_DIM/64), 256, 0, stream>>>(xn_h, xnT_h, NTOT, D_DIM);

  // slots = mu + exp(ls)*noise; tmp2 = LN(slots, ns)
  slotsinit_k<<<128, 256, 0, stream>>>(noise, init_mu, init_ls, ns_g, ns_b,
                                       slots, tmp2_h);

  for (int it=0; it<4; ++it){
    // q_eff = LN(slots,ns) @ (Wq Wk^T)
    mgemm64_k<1><<<dim3(8, 12), 256, 0, stream>>>(tmp2_h, BtQK, q_h, 512, 768, 768, 6);
    // dots = q_eff @ xn^T + inverted softmax
    dots_k<<<dim3(NB, 16), 256, 0, stream>>>(q_h, xn_h, attn_h, rsPart);
    // t = (attn @ xn) / rowsum
    attnv_k<<<dim3(NB, 12), 256, 0, stream>>>(attn_h, rsPart, xnT_h, t_h);
    // upd = t @ Wv
    mgemm64_k<0><<<dim3(8, 12), 256, 0, stream>>>(t_h, WvT, upd, 512, 768, 768, 6);
    // hbuf = LN(slots+upd, nica); tmp = LN(hbuf, ln1)
    lnlnw_k<<<128, 256, 0, stream>>>(slots, upd, nica_g, nica_b, ln1_g, ln1_b,
                                     hbuf, tmp_h);
    // qkv = a @ [Wq_a|Wk_a|Wv_a]
    mgemm64_k<1><<<dim3(8, 24), 256, 0, stream>>>(tmp_h, WqkvT, qkv_h, 512, 1536, 768, 6);
    encattn_k<<<dim3(NB, 8), 256, 0, stream>>>(qkv_h, qkv_h + 512, qkv_h + 1024, 1536, o_h);
    // obuf = o @ Wo_a (unsplit, plain store)
    mgemm64_k<0><<<dim3(8, 12), 256, 0, stream>>>(o_h, WoaT, obuf, 512, 768, 512, 4);
    // hbuf += obuf (written back); tmp = LN(hbuf, ln2)
    lnaddwb_k<<<128, 256, 0, stream>>>(hbuf, obuf, ln2_g, ln2_b, tmp_h);
    // act = glu(f @ W1)
    w1glu_k<<<dim3(8, 48), 256, 0, stream>>>(tmp_h, W1T, act_h, 512);
    // w2out = act @ W2 (unsplit K=3072, plain store)
    mgemm64_k<0><<<dim3(8, 12), 256, 0, stream>>>(act_h, W2T, w2out, 512, 768, 3072, 24);
    // slots = LN(hbuf+w2out, lnf); tmp2 = LN(slots, ns)
    lnlnw_k<<<128, 256, 0, stream>>>(hbuf, w2out, lnf_g, lnf_b, ns_g, ns_b,
                                     slots, tmp2_h);
  }

  hipMemcpyAsync(d_out, slots, (size_t)512*768*4, hipMemcpyDeviceToDevice, stream);
  attnout_k<<<NB*NTOK*NSLOT/256, 256, 0, stream>>>(attn_h, rsPart, (float*)d_out + 512*768);
}

// Round 3
// 627.903 us; speedup vs baseline: 1.1359x; 1.1050x over previous
//
#include <hip/hip_runtime.h>
#include <hip/hip_bf16.h>
#include <stdint.h>

typedef _Float16 f16;
typedef __attribute__((ext_vector_type(8))) _Float16 f16x8;
typedef __attribute__((ext_vector_type(4))) _Float16 f16x4;
typedef __attribute__((ext_vector_type(4))) float f32x4;

#define GLOBAL_AS __attribute__((address_space(1)))
#define LDS_AS __attribute__((address_space(3)))

#define D_DIM 768
#define NTOK 1024
#define NSLOT 16
#define NB 32
#define NTOT (NB*NTOK)   // 32768
#define HDIM 512
#define INNER 3072
#define SCALE_D 0.03608439182435161f   // 768^-0.5
#define SCALE_H 0.125f                 // 64^-0.5

// ---------- MFMA GEMM 64x64, BK=128 (4 panels), split-K ----------
// OUT: 0 = f32 store, 1 = f16 store, 2 = f32 atomicAdd.
template<int OUT>
__global__ __launch_bounds__(256) void mgemm64_k(
    const f16* __restrict__ A, const f16* __restrict__ Bt,
    void* __restrict__ Cout, int M, int N, int K, int Kc)
{
  __shared__ __align__(16) f16 As[64*128];
  __shared__ __align__(16) f16 Bs[64*128];
  const int tid = threadIdx.x;
  const int lane = tid & 63;
  const int wave = tid >> 6;
  const int m0 = blockIdx.x*64, n0 = blockIdx.y*64;
  const int kbeg = blockIdx.z * Kc;
  const int wm = (wave>>1)*32, wn = (wave&1)*32;
  const int quad = lane>>4, l16 = lane&15;

  const int sr = tid>>2;
  const int sc = (tid&3)*8;
  const f16* gA = A  + (size_t)(m0+sr)*K + kbeg + sc;
  const f16* gB = Bt + (size_t)(n0+sr)*K + kbeg + sc;
  LDS_AS f16* lA = (LDS_AS f16*)&As[(size_t)tid*8];
  LDS_AS f16* lB = (LDS_AS f16*)&Bs[(size_t)tid*8];

  const f16* fA0 = &As[(wm + l16)*32 + quad*8];
  const f16* fB0 = &Bs[(wn + l16)*32 + quad*8];

  f32x4 acc[2][2] = {};

  for (int k0 = 0; k0 < Kc; k0 += 128){
    #pragma unroll
    for (int p=0;p<4;++p){
      __builtin_amdgcn_global_load_lds((const GLOBAL_AS void*)(gA + k0 + p*32),
                                       (LDS_AS void*)(lA + (size_t)p*2048), 16, 0, 0);
      __builtin_amdgcn_global_load_lds((const GLOBAL_AS void*)(gB + k0 + p*32),
                                       (LDS_AS void*)(lB + (size_t)p*2048), 16, 0, 0);
    }
    __syncthreads();
    #pragma unroll
    for (int p=0;p<4;++p){
      f16x8 a0 = *(const f16x8*)(fA0 + p*2048);
      f16x8 a1 = *(const f16x8*)(fA0 + p*2048 + 16*32);
      f16x8 b0 = *(const f16x8*)(fB0 + p*2048);
      f16x8 b1 = *(const f16x8*)(fB0 + p*2048 + 16*32);
      acc[0][0] = __builtin_amdgcn_mfma_f32_16x16x32_f16(a0,b0,acc[0][0],0,0,0);
      acc[0][1] = __builtin_amdgcn_mfma_f32_16x16x32_f16(a0,b1,acc[0][1],0,0,0);
      acc[1][0] = __builtin_amdgcn_mfma_f32_16x16x32_f16(a1,b0,acc[1][0],0,0,0);
      acc[1][1] = __builtin_amdgcn_mfma_f32_16x16x32_f16(a1,b1,acc[1][1],0,0,0);
    }
    __syncthreads();
  }
  #pragma unroll
  for (int mt=0;mt<2;++mt){
    #pragma unroll
    for (int nt=0;nt<2;++nt){
      int gm = m0 + wm + mt*16 + quad*4;
      int gn = n0 + wn + nt*16 + l16;
      #pragma unroll
      for (int r=0;r<4;++r){
        float c = acc[mt][nt][r];
        size_t idx = (size_t)(gm+r)*N + gn;
        if (OUT==0)      ((float*)Cout)[idx] = c;
        else if (OUT==1) ((f16*)Cout)[idx] = (f16)c;
        else             atomicAdd(&((float*)Cout)[idx], c);
      }
    }
  }
}

// ---------- W1 + GLU fused ----------
__global__ __launch_bounds__(256) void w1glu_k(
    const f16* __restrict__ A, const f16* __restrict__ W1T,
    f16* __restrict__ act, int M)
{
  __shared__ __align__(16) f16 As[64*128];
  __shared__ __align__(16) f16 Bu[64*128];
  __shared__ __align__(16) f16 Bg[64*128];
  const int K = 768;
  const int tid = threadIdx.x;
  const int lane = tid & 63;
  const int wave = tid >> 6;
  const int m0 = blockIdx.x*64, n0 = blockIdx.y*64;
  const int wm = (wave>>1)*32, wn = (wave&1)*32;
  const int quad = lane>>4, l16 = lane&15;

  const int sr = tid>>2;
  const int sc = (tid&3)*8;
  const f16* gA  = A   + (size_t)(m0+sr)*K + sc;
  const f16* gBu = W1T + (size_t)(n0+sr)*K + sc;
  const f16* gBg = W1T + (size_t)(3072+n0+sr)*K + sc;
  LDS_AS f16* lA  = (LDS_AS f16*)&As[(size_t)tid*8];
  LDS_AS f16* lBu = (LDS_AS f16*)&Bu[(size_t)tid*8];
  LDS_AS f16* lBg = (LDS_AS f16*)&Bg[(size_t)tid*8];

  const f16* fA0 = &As[(wm + l16)*32 + quad*8];
  const f16* fU0 = &Bu[(wn + l16)*32 + quad*8];
  const f16* fG0 = &Bg[(wn + l16)*32 + quad*8];

  f32x4 accU[2][2] = {};
  f32x4 accG[2][2] = {};

  for (int k0 = 0; k0 < K; k0 += 128){
    #pragma unroll
    for (int p=0;p<4;++p){
      __builtin_amdgcn_global_load_lds((const GLOBAL_AS void*)(gA  + k0 + p*32),
                                       (LDS_AS void*)(lA  + (size_t)p*2048), 16, 0, 0);
      __builtin_amdgcn_global_load_lds((const GLOBAL_AS void*)(gBu + k0 + p*32),
                                       (LDS_AS void*)(lBu + (size_t)p*2048), 16, 0, 0);
      __builtin_amdgcn_global_load_lds((const GLOBAL_AS void*)(gBg + k0 + p*32),
                                       (LDS_AS void*)(lBg + (size_t)p*2048), 16, 0, 0);
    }
    __syncthreads();
    #pragma unroll
    for (int p=0;p<4;++p){
      f16x8 a0 = *(const f16x8*)(fA0 + p*2048);
      f16x8 a1 = *(const f16x8*)(fA0 + p*2048 + 16*32);
      f16x8 u0 = *(const f16x8*)(fU0 + p*2048);
      f16x8 u1 = *(const f16x8*)(fU0 + p*2048 + 16*32);
      f16x8 g0 = *(const f16x8*)(fG0 + p*2048);
      f16x8 g1 = *(const f16x8*)(fG0 + p*2048 + 16*32);
      accU[0][0] = __builtin_amdgcn_mfma_f32_16x16x32_f16(a0,u0,accU[0][0],0,0,0);
      accU[0][1] = __builtin_amdgcn_mfma_f32_16x16x32_f16(a0,u1,accU[0][1],0,0,0);
      accU[1][0] = __builtin_amdgcn_mfma_f32_16x16x32_f16(a1,u0,accU[1][0],0,0,0);
      accU[1][1] = __builtin_amdgcn_mfma_f32_16x16x32_f16(a1,u1,accU[1][1],0,0,0);
      accG[0][0] = __builtin_amdgcn_mfma_f32_16x16x32_f16(a0,g0,accG[0][0],0,0,0);
      accG[0][1] = __builtin_amdgcn_mfma_f32_16x16x32_f16(a0,g1,accG[0][1],0,0,0);
      accG[1][0] = __builtin_amdgcn_mfma_f32_16x16x32_f16(a1,g0,accG[1][0],0,0,0);
      accG[1][1] = __builtin_amdgcn_mfma_f32_16x16x32_f16(a1,g1,accG[1][1],0,0,0);
    }
    __syncthreads();
  }
  #pragma unroll
  for (int mt=0;mt<2;++mt){
    #pragma unroll
    for (int nt=0;nt<2;++nt){
      int gm = m0 + wm + mt*16 + quad*4;
      int gn = n0 + wn + nt*16 + l16;
      #pragma unroll
      for (int r=0;r<4;++r){
        float u = accU[mt][nt][r];
        float g = accG[mt][nt][r];
        float sg = g / (1.0f + __expf(-g));
        act[(size_t)(gm+r)*INNER + gn] = (f16)(u*sg);
      }
    }
  }
}

// ---------- MFMA dots (q_eff @ xn^T) + inverted softmax + EPS + partial rowsum ----------
__global__ __launch_bounds__(256) void dots_k(
    const f16* __restrict__ Q,    // [32,16,768] q_eff
    const f16* __restrict__ Xn,   // [32768,768]
    f16* __restrict__ attn,       // [32,16,1024] f16
    float* __restrict__ rsPart)   // [32][16 jt][16 i]
{
  __shared__ __align__(16) f16 qf[16*768];    // A-frag layout, 24 KB
  __shared__ __align__(16) f16 ks[64*128];    // 4 panels [64][32], 16 KB
  __shared__ float rpart[4][16];
  const int b = blockIdx.x, jt = blockIdx.y;
  const int tid = threadIdx.x;
  const int lane = tid & 63;
  const int w = tid >> 6;
  const int quad = lane>>4, l16 = lane&15;

  #pragma unroll
  for (int c=0;c<6;++c){
    int p = c*256 + tid;
    int ki = p >> 6, qd = (p >> 4) & 3, rw = p & 15;
    f16x8 v = *(const f16x8*)(Q + ((size_t)(b*NSLOT+rw))*D_DIM + ki*32 + qd*8);
    *(f16x8*)&qf[(size_t)p*8] = v;
  }

  const f16* gK = Xn + ((size_t)(b*NTOK + jt*64 + (tid>>2)))*D_DIM + (tid&3)*8;
  LDS_AS f16* lK = (LDS_AS f16*)&ks[(size_t)tid*8];

  f32x4 acc = {};
  for (int it=0; it<6; ++it){
    #pragma unroll
    for (int p=0;p<4;++p)
      __builtin_amdgcn_global_load_lds((const GLOBAL_AS void*)(gK + it*128 + p*32),
                                       (LDS_AS void*)(lK + (size_t)p*2048), 16, 0, 0);
    __syncthreads();
    #pragma unroll
    for (int p=0;p<4;++p){
      f16x8 a  = *(const f16x8*)&qf[(((size_t)(it*4+p)*4 + quad)*16 + l16)*8];
      f16x8 bf = *(const f16x8*)&ks[(size_t)p*2048 + (w*16+l16)*32 + quad*8];
      acc = __builtin_amdgcn_mfma_f32_16x16x32_f16(a, bf, acc, 0, 0, 0);
    }
    __syncthreads();
  }

  float v0 = acc[0]*SCALE_D, v1 = acc[1]*SCALE_D, v2 = acc[2]*SCALE_D, v3 = acc[3]*SCALE_D;
  float mx = fmaxf(fmaxf(v0,v1), fmaxf(v2,v3));
  mx = fmaxf(mx, __shfl_xor(mx, 16));
  mx = fmaxf(mx, __shfl_xor(mx, 32));
  float e0 = __expf(v0-mx), e1 = __expf(v1-mx), e2 = __expf(v2-mx), e3 = __expf(v3-mx);
  float s = e0+e1+e2+e3;
  s += __shfl_xor(s, 16);
  s += __shfl_xor(s, 32);
  float inv = 1.0f/s;
  float a0 = e0*inv + 1e-8f, a1 = e1*inv + 1e-8f, a2 = e2*inv + 1e-8f, a3 = e3*inv + 1e-8f;

  int jcol = jt*64 + w*16 + l16;
  int ibase = b*NSLOT + quad*4;
  attn[(size_t)(ibase+0)*NTOK + jcol] = (f16)a0;
  attn[(size_t)(ibase+1)*NTOK + jcol] = (f16)a1;
  attn[(size_t)(ibase+2)*NTOK + jcol] = (f16)a2;
  attn[(size_t)(ibase+3)*NTOK + jcol] = (f16)a3;

  float t0=a0, t1=a1, t2=a2, t3=a3;
  #pragma unroll
  for (int m=1;m<16;m<<=1){
    t0 += __shfl_xor(t0, m);
    t1 += __shfl_xor(t1, m);
    t2 += __shfl_xor(t2, m);
    t3 += __shfl_xor(t3, m);
  }
  if (l16 == 0){
    rpart[w][quad*4+0] = t0;
    rpart[w][quad*4+1] = t1;
    rpart[w][quad*4+2] = t2;
    rpart[w][quad*4+3] = t3;
  }
  __syncthreads();
  if (tid < 16){
    float ss = rpart[0][tid] + rpart[1][tid] + rpart[2][tid] + rpart[3][tid];
    rsPart[(size_t)((b*16 + jt)<<4) + tid] = ss;
  }
}

// ---------- t = (attn @ xn) / rowsum via MFMA on xnT; t -> f16 ----------
__global__ __launch_bounds__(256) void attnv_k(
    const f16* __restrict__ attn,   // [32,16,1024] f16
    const float* __restrict__ rsPart,
    const f16* __restrict__ XnT,    // [768, 32768]
    f16* __restrict__ t_out)        // [32,16,768] f16
{
  __shared__ __align__(16) f16 Asl[16*128];
  __shared__ __align__(16) f16 Bsl[64*128];
  __shared__ float rsum[16];
  const int b = blockIdx.x, d0 = blockIdx.y*64;
  const int tid = threadIdx.x;
  const int lane = tid & 63;
  const int w = tid >> 6;
  const int quad = lane>>4, l16 = lane&15;

  if (tid < 16){
    float s = 0.f;
    #pragma unroll
    for (int jt=0;jt<16;++jt) s += rsPart[(size_t)((b*16 + jt)<<4) + tid];
    rsum[tid] = s;
  }

  const int pa = tid>>6, ta = tid&63;
  const f16* gA = attn + ((size_t)(b*NSLOT + (ta>>2)))*NTOK + pa*32 + (ta&3)*8;
  LDS_AS f16* lA = (LDS_AS f16*)&Asl[(size_t)pa*512 + ta*8];
  const f16* gB = XnT + ((size_t)(d0 + (tid>>2)))*NTOT + b*NTOK + (tid&3)*8;
  LDS_AS f16* lB = (LDS_AS f16*)&Bsl[(size_t)tid*8];

  f32x4 acc = {};
  for (int it=0; it<8; ++it){
    __builtin_amdgcn_global_load_lds((const GLOBAL_AS void*)(gA + it*128),
                                     (LDS_AS void*)lA, 16, 0, 0);
    #pragma unroll
    for (int p=0;p<4;++p)
      __builtin_amdgcn_global_load_lds((const GLOBAL_AS void*)(gB + it*128 + p*32),
                                       (LDS_AS void*)(lB + (size_t)p*2048), 16, 0, 0);
    __syncthreads();
    #pragma unroll
    for (int p=0;p<4;++p){
      f16x8 a  = *(const f16x8*)&Asl[(size_t)p*512 + l16*32 + quad*8];
      f16x8 bf = *(const f16x8*)&Bsl[(size_t)p*2048 + (w*16+l16)*32 + quad*8];
      acc = __builtin_amdgcn_mfma_f32_16x16x32_f16(a, bf, acc, 0, 0, 0);
    }
    __syncthreads();
  }
  int dcol = d0 + w*16 + l16;
  #pragma unroll
  for (int r=0;r<4;++r){
    int i = quad*4 + r;
    t_out[(size_t)(b*NSLOT + i)*D_DIM + dcol] = (f16)(acc[r] / rsum[i]);
  }
}

// ---------- wave-per-row LN (4 rows/block), f16 out ----------
__global__ __launch_bounds__(256) void lnw_k(
    const float* __restrict__ X,
    const float* __restrict__ g, const float* __restrict__ bb,
    f16* __restrict__ out)
{
  const int lane = threadIdx.x & 63;
  const size_t row = (size_t)blockIdx.x*4 + (threadIdx.x>>6);
  const float* x = X + row*D_DIM;
  float4 v[3]; float s=0.f, ss=0.f;
  #pragma unroll
  for (int t=0;t<3;++t){
    v[t] = *(const float4*)(x + lane*4 + t*256);
    s  += v[t].x+v[t].y+v[t].z+v[t].w;
    ss += v[t].x*v[t].x+v[t].y*v[t].y+v[t].z*v[t].z+v[t].w*v[t].w;
  }
  #pragma unroll
  for (int m=1;m<64;m<<=1){ s += __shfl_xor(s,m); ss += __shfl_xor(ss,m); }
  float mean = s*(1.0f/768.0f);
  float inv  = rsqrtf(ss*(1.0f/768.0f) - mean*mean + 1e-5f);
  #pragma unroll
  for (int t=0;t<3;++t){
    int c0 = lane*4 + t*256;
    float4 gg = *(const float4*)(g + c0);
    float4 bv = *(const float4*)(bb + c0);
    f16x4 h4;
    h4.x = (f16)((v[t].x-mean)*inv*gg.x + bv.x);
    h4.y = (f16)((v[t].y-mean)*inv*gg.y + bv.y);
    h4.z = (f16)((v[t].z-mean)*inv*gg.z + bv.z);
    h4.w = (f16)((v[t].w-mean)*inv*gg.w + bv.w);
    *(f16x4*)(out + row*D_DIM + c0) = h4;
  }
}

// ---------- wave-per-row double LN: out1=LN(X[+X2],g1,b1) f32, out2=LN(out1,g2,b2) f16 ----------
template<bool ADD>
__global__ __launch_bounds__(256) void lnlnw_k(
    const float* __restrict__ X, const float* __restrict__ X2,
    const float* __restrict__ g1, const float* __restrict__ b1,
    const float* __restrict__ g2, const float* __restrict__ b2,
    float* __restrict__ out1, f16* __restrict__ out2)
{
  const int lane = threadIdx.x & 63;
  const size_t row = (size_t)blockIdx.x*4 + (threadIdx.x>>6);
  const float* x = X + row*D_DIM;
  const float* x2 = X2 + row*D_DIM;
  float4 v[3]; float s=0.f, ss=0.f;
  #pragma unroll
  for (int t=0;t<3;++t){
    int c0 = lane*4 + t*256;
    float4 a = *(const float4*)(x + c0);
    if (ADD){
      float4 b = *(const float4*)(x2 + c0);
      a.x+=b.x; a.y+=b.y; a.z+=b.z; a.w+=b.w;
    }
    v[t]=a;
    s  += v[t].x+v[t].y+v[t].z+v[t].w;
    ss += v[t].x*v[t].x+v[t].y*v[t].y+v[t].z*v[t].z+v[t].w*v[t].w;
  }
  #pragma unroll
  for (int m=1;m<64;m<<=1){ s += __shfl_xor(s,m); ss += __shfl_xor(ss,m); }
  float mean = s*(1.0f/768.0f);
  float inv  = rsqrtf(ss*(1.0f/768.0f) - mean*mean + 1e-5f);
  float y[3][4]; float s2=0.f, ss2=0.f;
  #pragma unroll
  for (int t=0;t<3;++t){
    int c0 = lane*4 + t*256;
    float4 gg = *(const float4*)(g1 + c0);
    float4 bv = *(const float4*)(b1 + c0);
    y[t][0] = (v[t].x-mean)*inv*gg.x + bv.x;
    y[t][1] = (v[t].y-mean)*inv*gg.y + bv.y;
    y[t][2] = (v[t].z-mean)*inv*gg.z + bv.z;
    y[t][3] = (v[t].w-mean)*inv*gg.w + bv.w;
    float4 o = { y[t][0], y[t][1], y[t][2], y[t][3] };
    *(float4*)(out1 + row*D_DIM + c0) = o;
    s2  += y[t][0]+y[t][1]+y[t][2]+y[t][3];
    ss2 += y[t][0]*y[t][0]+y[t][1]*y[t][1]+y[t][2]*y[t][2]+y[t][3]*y[t][3];
  }
  #pragma unroll
  for (int m=1;m<64;m<<=1){ s2 += __shfl_xor(s2,m); ss2 += __shfl_xor(ss2,m); }
  float mean2 = s2*(1.0f/768.0f);
  float inv2  = rsqrtf(ss2*(1.0f/768.0f) - mean2*mean2 + 1e-5f);
  #pragma unroll
  for (int t=0;t<3;++t){
    int c0 = lane*4 + t*256;
    float4 gg = *(const float4*)(g2 + c0);
    float4 bv = *(const float4*)(b2 + c0);
    f16x4 h4;
    h4.x = (f16)((y[t][0]-mean2)*inv2*gg.x + bv.x);
    h4.y = (f16)((y[t][1]-mean2)*inv2*gg.y + bv.y);
    h4.z = (f16)((y[t][2]-mean2)*inv2*gg.z + bv.z);
    h4.w = (f16)((y[t][3]-mean2)*inv2*gg.w + bv.w);
    *(f16x4*)(out2 + row*D_DIM + c0) = h4;
  }
}

// ---------- slots init + LN(ns) fused ----------
__global__ __launch_bounds__(256) void slotsinit_k(
    const float* __restrict__ noise, const float* __restrict__ mu,
    const float* __restrict__ ls,
    const float* __restrict__ nsg, const float* __restrict__ nsb,
    float* __restrict__ slots, f16* __restrict__ tmp2)
{
  const int lane = threadIdx.x & 63;
  const size_t row = (size_t)blockIdx.x*4 + (threadIdx.x>>6);
  float4 v[3]; float s=0.f, ss=0.f;
  #pragma unroll
  for (int t=0;t<3;++t){
    int c0 = lane*4 + t*256;
    float4 nz = *(const float4*)(noise + row*D_DIM + c0);
    float4 m4 = *(const float4*)(mu + c0);
    float4 l4 = *(const float4*)(ls + c0);
    v[t].x = m4.x + __expf(l4.x)*nz.x;
    v[t].y = m4.y + __expf(l4.y)*nz.y;
    v[t].z = m4.z + __expf(l4.z)*nz.z;
    v[t].w = m4.w + __expf(l4.w)*nz.w;
    *(float4*)(slots + row*D_DIM + c0) = v[t];
    s  += v[t].x+v[t].y+v[t].z+v[t].w;
    ss += v[t].x*v[t].x+v[t].y*v[t].y+v[t].z*v[t].z+v[t].w*v[t].w;
  }
  #pragma unroll
  for (int m=1;m<64;m<<=1){ s += __shfl_xor(s,m); ss += __shfl_xor(ss,m); }
  float mean = s*(1.0f/768.0f);
  float inv  = rsqrtf(ss*(1.0f/768.0f) - mean*mean + 1e-5f);
  #pragma unroll
  for (int t=0;t<3;++t){
    int c0 = lane*4 + t*256;
    float4 gg = *(const float4*)(nsg + c0);
    float4 bv = *(const float4*)(nsb + c0);
    f16x4 h4;
    h4.x = (f16)((v[t].x-mean)*inv*gg.x + bv.x);
    h4.y = (f16)((v[t].y-mean)*inv*gg.y + bv.y);
    h4.z = (f16)((v[t].z-mean)*inv*gg.z + bv.z);
    h4.w = (f16)((v[t].w-mean)*inv*gg.w + bv.w);
    *(f16x4*)(tmp2 + row*D_DIM + c0) = h4;
  }
}

// ---------- encoder self-attention ----------
__global__ __launch_bounds__(256) void encattn_k(
    const f16* __restrict__ QA, const f16* __restrict__ KA,
    const f16* __restrict__ VA, int QSTR,
    f16* __restrict__ O)
{
  __shared__ float qs[16][68], ks[16][68], vs[16][68], ps[16][20];
  const int b = blockIdx.x, h = blockIdx.y;
  const int tid = threadIdx.x;
  {
    int i = tid>>4, dd=(tid&15)*4;
    size_t base = ((size_t)(b*NSLOT+i))*QSTR + h*64 + dd;
    f16x4 uq = *(const f16x4*)(QA + base);
    f16x4 uk = *(const f16x4*)(KA + base);
    f16x4 uv = *(const f16x4*)(VA + base);
    float4 fq = { (float)uq.x, (float)uq.y, (float)uq.z, (float)uq.w };
    float4 fk = { (float)uk.x, (float)uk.y, (float)uk.z, (float)uk.w };
    float4 fv = { (float)uv.x, (float)uv.y, (float)uv.z, (float)uv.w };
    *(float4*)&qs[i][dd]=fq; *(float4*)&ks[i][dd]=fk; *(float4*)&vs[i][dd]=fv;
  }
  __syncthreads();
  {
    int i = tid>>4, j = tid&15;
    float s=0.f;
    #pragma unroll 8
    for (int d=0; d<64; ++d) s += qs[i][d]*ks[j][d];
    ps[i][j] = s*SCALE_H;
  }
  __syncthreads();
  if (tid < 16){
    int i = tid;
    float mx=-1e30f;
    #pragma unroll
    for (int j=0;j<16;++j) mx = fmaxf(mx, ps[i][j]);
    float sm=0.f;
    #pragma unroll
    for (int j=0;j<16;++j){ float e=__expf(ps[i][j]-mx); ps[i][j]=e; sm+=e; }
    float inv=1.0f/sm;
    #pragma unroll
    for (int j=0;j<16;++j) ps[i][j]*=inv;
  }
  __syncthreads();
  {
    int i = tid>>4, dq=(tid&15)*4;
    float a0=0,a1=0,a2=0,a3=0;
    #pragma unroll
    for (int j=0;j<16;++j){
      float p = ps[i][j];
      a0+=p*vs[j][dq+0]; a1+=p*vs[j][dq+1]; a2+=p*vs[j][dq+2]; a3+=p*vs[j][dq+3];
    }
    size_t base = ((size_t)(b*NSLOT+i))*HDIM + h*64 + dq;
    O[base+0]=(f16)a0; O[base+1]=(f16)a1; O[base+2]=(f16)a2; O[base+3]=(f16)a3;
  }
}

// ---------- f16 transpose: out[C][R] = in[R][C] ----------
__global__ __launch_bounds__(256) void transp_k(
    const f16* __restrict__ in, f16* __restrict__ out, int R, int C)
{
  __shared__ f16 T[64][72];
  const int m0 = blockIdx.x*64, d0 = blockIdx.y*64;
  const int tid = threadIdx.x;
  {
    int r = tid>>2, c = (tid&3)*16;
    const f16* p = in + (size_t)(m0+r)*C + d0 + c;
    *(f16x8*)&T[r][c]   = *(const f16x8*)p;
    *(f16x8*)&T[r][c+8] = *(const f16x8*)(p+8);
  }
  __syncthreads();
  {
    int dd = tid>>2, mq = (tid&3)*16;
    f16 v[16];
    #pragma unroll
    for (int e=0;e<16;++e) v[e] = T[mq+e][dd];
    f16* p = out + (size_t)(d0+dd)*R + m0 + mq;
    *(f16x8*)p     = *(f16x8*)&v[0];
    *(f16x8*)(p+8) = *(f16x8*)&v[8];
  }
}

// ---------- all weight casts/transposes in ONE kernel ----------
__global__ __launch_bounds__(256) void prep_k(
    const float* __restrict__ Wv,   const float* __restrict__ Wq_a,
    const float* __restrict__ Wk_a, const float* __restrict__ Wv_a,
    const float* __restrict__ Wo_a, const float* __restrict__ W1,
    const float* __restrict__ W2,   const float* __restrict__ Wk,
    const float* __restrict__ Wq,
    f16* __restrict__ WvT, f16* __restrict__ WqkvT, f16* __restrict__ WoaT,
    f16* __restrict__ W1T, f16* __restrict__ W2T,
    f16* __restrict__ Wkf, f16* __restrict__ Wqf)
{
  __shared__ float t[32][33];
  int bid = blockIdx.x;
  const float* src; f16* dst; int R, C; bool tr = true;
  if      (bid < 576)  {              src=Wv;   dst=WvT;             R=768;  C=768; }
  else if (bid < 960)  { bid-=576;    src=Wq_a; dst=WqkvT;           R=768;  C=512; }
  else if (bid < 1344) { bid-=960;    src=Wk_a; dst=WqkvT+512*768;   R=768;  C=512; }
  else if (bid < 1728) { bid-=1344;   src=Wv_a; dst=WqkvT+1024*768;  R=768;  C=512; }
  else if (bid < 2112) { bid-=1728;   src=Wo_a; dst=WoaT;            R=512;  C=768; }
  else if (bid < 6720) { bid-=2112;   src=W1;   dst=W1T;             R=768;  C=6144; }
  else if (bid < 9024) { bid-=6720;   src=W2;   dst=W2T;             R=3072; C=768; }
  else if (bid < 9600) { bid-=9024;   src=Wk;   dst=Wkf;             R=768;  C=768; tr=false; }
  else                 { bid-=9600;   src=Wq;   dst=Wqf;             R=768;  C=768; tr=false; }
  const int tpr = C/32;
  const int r0 = (bid / tpr)*32, c0 = (bid % tpr)*32;
  const int lc = threadIdx.x & 31, g8 = threadIdx.x >> 5;
  if (tr){
    #pragma unroll
    for (int s=0;s<4;++s){
      int r = g8*4 + s;
      t[r][lc] = src[(size_t)(r0+r)*C + c0+lc];
    }
    __syncthreads();
    #pragma unroll
    for (int s=0;s<4;++s){
      int c = g8*4 + s;
      dst[(size_t)(c0+c)*R + r0+lc] = (f16)t[lc][c];
    }
  } else {
    #pragma unroll
    for (int s=0;s<4;++s){
      int r = g8*4 + s;
      dst[(size_t)(r0+r)*C + c0+lc] = (f16)src[(size_t)(r0+r)*C + c0+lc];
    }
  }
}

// ---------- attn_map output (rowsum inline) ----------
__global__ __launch_bounds__(256) void attnout_k(
    const f16* __restrict__ attn, const float* __restrict__ rsPart,
    float* __restrict__ out)
{
  __shared__ float rsum[16];
  const int bid = blockIdx.x, tid = threadIdx.x;
  const int b = bid >> 6;
  if (tid < 16){
    float s = 0.f;
    #pragma unroll
    for (int jt=0;jt<16;++jt) s += rsPart[(size_t)((b*16+jt)<<4) + tid];
    rsum[tid] = s;
  }
  __syncthreads();
  int idx = bid*256 + tid;
  int i = idx & 15;
  int j = (idx >> 4) & 1023;
  out[idx] = (float)attn[((size_t)(b*NSLOT)+i)*NTOK + j] / rsum[i];
}

extern "C" void kernel_launch(void* const* d_in, const int* in_sizes, int n_in,
                              void* d_out, int out_size, void* d_ws, size_t ws_size,
                              hipStream_t stream) {
  const float* x        = (const float*)d_in[0];
  const float* noise    = (const float*)d_in[1];
  const float* init_mu  = (const float*)d_in[2];
  const float* init_ls  = (const float*)d_in[3];
  const float* Wk       = (const float*)d_in[4];
  const float* Wv       = (const float*)d_in[5];
  const float* Wq       = (const float*)d_in[6];
  const float* ni_g     = (const float*)d_in[7];
  const float* ni_b     = (const float*)d_in[8];
  const float* ns_g     = (const float*)d_in[9];
  const float* ns_b     = (const float*)d_in[10];
  const float* nica_g   = (const float*)d_in[11];
  const float* nica_b   = (const float*)d_in[12];
  const float* ln1_g    = (const float*)d_in[13];
  const float* ln1_b    = (const float*)d_in[14];
  const float* Wq_a     = (const float*)d_in[15];
  const float* Wk_a     = (const float*)d_in[16];
  const float* Wv_a     = (const float*)d_in[17];
  const float* Wo_a     = (const float*)d_in[18];
  const float* ln2_g    = (const float*)d_in[19];
  const float* ln2_b    = (const float*)d_in[20];
  const float* W1       = (const float*)d_in[21];
  const float* W2       = (const float*)d_in[22];
  const float* lnf_g    = (const float*)d_in[23];
  const float* lnf_b    = (const float*)d_in[24];

  char* w = (char*)d_ws;
  size_t off = 0;
  auto alloc = [&](size_t bytes)->char*{
    char* p = w + off; off += (bytes + 255) & ~(size_t)255; return p;
  };
  f16* xn_h  = (f16*)alloc((size_t)NTOT*D_DIM*2);
  f16* xnT_h = (f16*)alloc((size_t)D_DIM*NTOT*2);
  f16* Wkf   = (f16*)alloc((size_t)768*768*2);
  f16* Wqf   = (f16*)alloc((size_t)768*768*2);
  f16* BtQK  = (f16*)alloc((size_t)768*768*2);
  f16* WvT   = (f16*)alloc((size_t)768*768*2);
  f16* WqkvT = (f16*)alloc((size_t)1536*768*2);
  f16* WoaT  = (f16*)alloc((size_t)768*512*2);
  f16* W1T   = (f16*)alloc((size_t)6144*768*2);
  f16* W2T   = (f16*)alloc((size_t)768*3072*2);
  float* slots = (float*)alloc(512*768*4);
  float* hbuf  = (float*)alloc(512*768*4);
  float* upd   = (float*)alloc(512*768*4);
  f16* tmp_h  = (f16*)alloc(512*768*2);
  f16* tmp2_h = (f16*)alloc(512*768*2);
  f16* q_h    = (f16*)alloc(512*768*2);
  f16* t_h    = (f16*)alloc(512*768*2);
  f16* qkv_h  = (f16*)alloc((size_t)512*1536*2);
  f16* o_h    = (f16*)alloc(512*512*2);
  f16* act_h  = (f16*)alloc((size_t)512*3072*2);
  f16* attn_h = (f16*)alloc((size_t)NB*NSLOT*NTOK*2);
  float* rsPart = (float*)alloc((size_t)32*16*16*4);

  // weight prep: all casts/transposes in one launch
  prep_k<<<10176, 256, 0, stream>>>(Wv, Wq_a, Wk_a, Wv_a, Wo_a, W1, W2, Wk, Wq,
                                    WvT, WqkvT, WoaT, W1T, W2T, Wkf, Wqf);

  // BtQK[f][e] = sum_d Wk[f][d] * Wq[e][d]
  mgemm64_k<1><<<dim3(12, 12, 1), 256, 0, stream>>>(Wkf, Wqf, BtQK, 768, 768, 768, 768);

  // xn = LN(x); xnT = xn^T
  lnw_k<<<NTOT/4, 256, 0, stream>>>(x, ni_g, ni_b, xn_h);
  transp_k<<<dim3(NTOT/64, D_DIM/64), 256, 0, stream>>>(xn_h, xnT_h, NTOT, D_DIM);

  // slots = mu + exp(ls)*noise; tmp2 = LN(slots, ns)
  slotsinit_k<<<128, 256, 0, stream>>>(noise, init_mu, init_ls, ns_g, ns_b,
                                       slots, tmp2_h);

  for (int it=0; it<4; ++it){
    // q_eff = LN(slots,ns) @ (Wq Wk^T)
    mgemm64_k<1><<<dim3(8, 12, 1), 256, 0, stream>>>(tmp2_h, BtQK, q_h, 512, 768, 768, 768);
    // dots = q_eff @ xn^T + inverted softmax
    dots_k<<<dim3(NB, 16), 256, 0, stream>>>(q_h, xn_h, attn_h, rsPart);
    // t = (attn @ xn) / rowsum
    attnv_k<<<dim3(NB, 12), 256, 0, stream>>>(attn_h, rsPart, xnT_h, t_h);
    // upd = t @ Wv
    mgemm64_k<0><<<dim3(8, 12, 1), 256, 0, stream>>>(t_h, WvT, upd, 512, 768, 768, 768);
    // hbuf = LN(slots+upd, nica); tmp = LN(hbuf, ln1)
    lnlnw_k<true><<<128, 256, 0, stream>>>(slots, upd, nica_g, nica_b, ln1_g, ln1_b,
                                           hbuf, tmp_h);
    // qkv = a @ [Wq_a|Wk_a|Wv_a]
    mgemm64_k<1><<<dim3(8, 24, 1), 256, 0, stream>>>(tmp_h, WqkvT, qkv_h, 512, 1536, 768, 768);
    encattn_k<<<dim3(NB, 8), 256, 0, stream>>>(qkv_h, qkv_h + 512, qkv_h + 1024, 1536, o_h);
    // hbuf += o @ Wo_a (split-K=2 atomic)
    mgemm64_k<2><<<dim3(8, 12, 2), 256, 0, stream>>>(o_h, WoaT, hbuf, 512, 768, 512, 256);
    // f = LN(hbuf, ln2)
    lnw_k<<<128, 256, 0, stream>>>(hbuf, ln2_g, ln2_b, tmp_h);
    // act = glu(f @ W1)
    w1glu_k<<<dim3(8, 48), 256, 0, stream>>>(tmp_h, W1T, act_h, 512);
    // hbuf += act @ W2 (split-K=4 atomic)
    mgemm64_k<2><<<dim3(8, 12, 4), 256, 0, stream>>>(act_h, W2T, hbuf, 512, 768, 3072, 768);
    // slots = LN(hbuf, lnf) [last iter: straight to d_out]; tmp2 = LN(slots, ns)
    float* out1 = (it==3) ? (float*)d_out : slots;
    lnlnw_k<false><<<128, 256, 0, stream>>>(hbuf, nullptr, lnf_g, lnf_b, ns_g, ns_b,
                                            out1, tmp2_h);
  }

  attnout_k<<<NB*NTOK*NSLOT/256, 256, 0, stream>>>(attn_h, rsPart, (float*)d_out + 512*768);
}